// Round 1
// baseline (371.529 us; speedup 1.0000x reference)
//
#include <hip/hip_runtime.h>
#include <cstdint>

// Problem constants
#define BB    8
#define CIN   256
#define COUT  256
#define HH    64
#define WW    64
#define HWSZ  4096          // H*W
#define NPIX  32768         // B*H*W
#define NTAP  9

typedef __attribute__((ext_vector_type(8))) short    s16x8;
typedef __attribute__((ext_vector_type(8))) unsigned short u16x8;
typedef __attribute__((ext_vector_type(4))) float    f32x4;

__device__ __forceinline__ float bf2f(unsigned short u) {
    unsigned int v = ((unsigned int)u) << 16;
    return __builtin_bit_cast(float, v);
}
__device__ __forceinline__ unsigned short f2bf(float f) {
    unsigned int u = __builtin_bit_cast(unsigned int, f);
    unsigned int r = (u + 0x7FFFu + ((u >> 16) & 1u)) >> 16;   // RNE
    return (unsigned short)r;
}

// ---------------------------------------------------------------------------
// 1) x [B,C,H,W] fp32  ->  xT [B,H,W,C] bf16   (LDS tile transpose per (b,h))
// blocks: B*H*(C/64) = 2048, 256 thr
__global__ void k_pack_x(const float* __restrict__ x, unsigned short* __restrict__ xT) {
    int blk = blockIdx.x;
    int c0 = (blk & 3) * 64;
    int h  = (blk >> 2) & 63;
    int b  = blk >> 8;
    __shared__ float tile[64][65];
    int t = threadIdx.x;
#pragma unroll
    for (int r = 0; r < 16; ++r) {
        int idx = t + r * 256;            // 0..4095
        int i = idx >> 6, w = idx & 63;   // i: c-row, w: col
        tile[i][w] = x[(((b * 256 + c0 + i) * 64 + h) * 64) + w];
    }
    __syncthreads();
#pragma unroll
    for (int r = 0; r < 16; ++r) {
        int idx = t + r * 256;
        int w = idx >> 6, c = idx & 63;
        xT[((b * 64 + h) * 64 + w) * 256 + c0 + c] = f2bf(tile[c][w]);
    }
}

// ---------------------------------------------------------------------------
// 2) weight [O,C,3,3] fp32 -> wT [tap][o][c] bf16   (589824 elems)
__global__ void k_pack_w(const float* __restrict__ w, unsigned short* __restrict__ wT) {
    int idx = blockIdx.x * 256 + threadIdx.x;   // = ((tp*256+o)*256+c)
    int c  = idx & 255;
    int o  = (idx >> 8) & 255;
    int tp = idx >> 16;
    wT[idx] = f2bf(w[(o * 256 + c) * 9 + tp]);
}

// 3) w_off [27,C,3,3] fp32 -> wofT [tap][j(32,pad0)][c] bf16  (73728 elems)
__global__ void k_pack_woff(const float* __restrict__ w, unsigned short* __restrict__ wT) {
    int idx = blockIdx.x * 256 + threadIdx.x;   // = ((tp*32+j)*256+c)
    int c  = idx & 255;
    int j  = (idx >> 8) & 31;
    int tp = idx >> 13;
    float v = (j < 27) ? w[(j * 256 + c) * 9 + tp] : 0.f;
    wT[idx] = f2bf(v);
}

// ---------------------------------------------------------------------------
// 4) offset conv: om[P][32] = conv(x, w_off)+b_off  (raw, no sigmoid)
// blocks: 512 (one per (b,h)); 256 thr = 4 waves; wave = 16 pixels x 32 j
__global__ __launch_bounds__(256, 2)
void k_offconv(const unsigned short* __restrict__ xT,
               const unsigned short* __restrict__ wofT,
               const float* __restrict__ b_off,
               float* __restrict__ om) {
    int blk = blockIdx.x;
    int b = blk >> 6, h = blk & 63;
    int P0 = blk * 64;
    int t = threadIdx.x;
    int lane = t & 63, wv = t >> 6;
    int p0w = wv * 16;
    int lm = lane & 15, q = lane >> 4;
    __shared__ unsigned short S[64 * 32];

    const f32x4 FZ = {0.f, 0.f, 0.f, 0.f};
    f32x4 acc0 = FZ, acc1 = FZ;

    int p_s  = t >> 2;          // staging pixel (=w)
    int cc_s = (t & 3) * 8;     // staging channel sub-chunk

    for (int tp = 0; tp < 9; ++tp) {
        int dh = tp / 3 - 1, dw = tp % 3 - 1;
        int hs = h + dh;
        int ws_ = p_s + dw;
        bool valid = (hs >= 0) & (hs < 64) & (ws_ >= 0) & (ws_ < 64);
        int hc = min(max(hs, 0), 63), wc = min(max(ws_, 0), 63);
        int src = ((b * 64 + hc) * 64 + wc) * 256 + cc_s;
        for (int c0 = 0; c0 < 256; c0 += 32) {
            __syncthreads();
            u16x8 v = *reinterpret_cast<const u16x8*>(xT + src + c0);
            if (!valid) { u16x8 z = {0,0,0,0,0,0,0,0}; v = z; }
            *reinterpret_cast<u16x8*>(&S[p_s * 32 + cc_s]) = v;
            __syncthreads();
            s16x8 a = *reinterpret_cast<const s16x8*>(&S[(p0w + lm) * 32 + q * 8]);
            const unsigned short* wb = wofT + (tp * 32 + lm) * 256 + c0 + q * 8;
            s16x8 b0 = *reinterpret_cast<const s16x8*>(wb);
            s16x8 b1 = *reinterpret_cast<const s16x8*>(wb + 16 * 256);
            acc0 = __builtin_amdgcn_mfma_f32_16x16x32_bf16(a, b0, acc0, 0, 0, 0);
            acc1 = __builtin_amdgcn_mfma_f32_16x16x32_bf16(a, b1, acc1, 0, 0, 0);
        }
    }
    // epilogue: D col = lane&15, row = q*4+i
#pragma unroll
    for (int n = 0; n < 2; ++n) {
        int j = n * 16 + lm;
        float bj = (j < 27) ? b_off[j] : 0.f;
        f32x4 a = n ? acc1 : acc0;
#pragma unroll
        for (int i = 0; i < 4; ++i) {
            int prow = p0w + q * 4 + i;
            om[(P0 + prow) * 32 + j] = a[i] + bj;
        }
    }
}

// ---------------------------------------------------------------------------
// 5) main deform GEMM: y[P][256] fp32
// blocks: 512 (one per (b,h) = 64 pixels); 256 thr = 4 waves (2x2)
// wave tile: 32 pixels x 128 out-ch = 2x8 MFMA tiles of 16x16
__global__ __launch_bounds__(256, 2)
void k_main(const unsigned short* __restrict__ xT,
            const unsigned short* __restrict__ wT,
            const float* __restrict__ om,
            const float* __restrict__ bias,
            float* __restrict__ y) {
    int blk = blockIdx.x;
    int b = blk >> 6, h = blk & 63;
    int P0 = blk * 64;
    int t = threadIdx.x;
    int lane = t & 63, wv = t >> 6;
    int p0w = (wv >> 1) * 32;
    int o0  = (wv & 1) * 128;
    int lm = lane & 15, q = lane >> 4;
    __shared__ unsigned short S[64 * 32];

    const f32x4 FZ = {0.f, 0.f, 0.f, 0.f};
    f32x4 acc[2][8];
#pragma unroll
    for (int m = 0; m < 2; ++m)
#pragma unroll
        for (int n = 0; n < 8; ++n) acc[m][n] = FZ;

    int p_s  = t >> 2;          // staging pixel (=w coordinate)
    int cc_s = (t & 3) * 8;     // staging channel sub-chunk
    int P = P0 + p_s;

    for (int tp = 0; tp < 9; ++tp) {
        // per-tap bilinear setup for the staging pixel
        float oh = om[P * 32 + 2 * tp];
        float ow = om[P * 32 + 2 * tp + 1];
        float mv = om[P * 32 + 18 + tp];
        float mk = 1.f / (1.f + __expf(-mv));
        float ph = (float)(h + tp / 3 - 1) + oh;
        float pw = (float)(p_s + tp % 3 - 1) + ow;
        float fh0 = floorf(ph), fw0 = floorf(pw);
        int ih0 = (int)fh0, iw0 = (int)fw0;
        float lh = ph - fh0, lw = pw - fw0;
        float hh = 1.f - lh, hw_ = 1.f - lw;
        bool vh0 = (ih0 >= 0) & (ih0 < 64);
        bool vh1 = (ih0 + 1 >= 0) & (ih0 + 1 < 64);
        bool vw0 = (iw0 >= 0) & (iw0 < 64);
        bool vw1 = (iw0 + 1 >= 0) & (iw0 + 1 < 64);
        float w00 = hh * hw_ * mk * (float)(vh0 & vw0);
        float w01 = hh * lw  * mk * (float)(vh0 & vw1);
        float w10 = lh * hw_ * mk * (float)(vh1 & vw0);
        float w11 = lh * lw  * mk * (float)(vh1 & vw1);
        int ch0 = min(max(ih0, 0), 63), ch1 = min(max(ih0 + 1, 0), 63);
        int cw0 = min(max(iw0, 0), 63), cw1 = min(max(iw0 + 1, 0), 63);
        int rb = b * 4096;
        int a00 = ((rb + ch0 * 64 + cw0) * 256) + cc_s;
        int a01 = ((rb + ch0 * 64 + cw1) * 256) + cc_s;
        int a10 = ((rb + ch1 * 64 + cw0) * 256) + cc_s;
        int a11 = ((rb + ch1 * 64 + cw1) * 256) + cc_s;

        for (int c0 = 0; c0 < 256; c0 += 32) {
            __syncthreads();
            // gather + bilinear blend + mask, pack to bf16, stage to LDS
            u16x8 r00 = *reinterpret_cast<const u16x8*>(xT + a00 + c0);
            u16x8 r01 = *reinterpret_cast<const u16x8*>(xT + a01 + c0);
            u16x8 r10 = *reinterpret_cast<const u16x8*>(xT + a10 + c0);
            u16x8 r11 = *reinterpret_cast<const u16x8*>(xT + a11 + c0);
            u16x8 res;
#pragma unroll
            for (int j = 0; j < 8; ++j) {
                float v = w00 * bf2f(r00[j]) + w01 * bf2f(r01[j])
                        + w10 * bf2f(r10[j]) + w11 * bf2f(r11[j]);
                res[j] = f2bf(v);
            }
            *reinterpret_cast<u16x8*>(&S[p_s * 32 + cc_s]) = res;
            __syncthreads();

            // fragments + MFMA
            s16x8 af0 = *reinterpret_cast<const s16x8*>(&S[(p0w + lm) * 32 + q * 8]);
            s16x8 af1 = *reinterpret_cast<const s16x8*>(&S[(p0w + 16 + lm) * 32 + q * 8]);
            const unsigned short* wb = wT + ((tp * 256 + o0 + lm) * 256) + c0 + q * 8;
#pragma unroll
            for (int nt = 0; nt < 8; ++nt) {
                s16x8 bf = *reinterpret_cast<const s16x8*>(wb + nt * 16 * 256);
                acc[0][nt] = __builtin_amdgcn_mfma_f32_16x16x32_bf16(af0, bf, acc[0][nt], 0, 0, 0);
                acc[1][nt] = __builtin_amdgcn_mfma_f32_16x16x32_bf16(af1, bf, acc[1][nt], 0, 0, 0);
            }
        }
    }

    // epilogue: y[P][o] = acc + bias[o]
#pragma unroll
    for (int nt = 0; nt < 8; ++nt) {
        int o = o0 + nt * 16 + lm;
        float bo = bias[o];
#pragma unroll
        for (int mt = 0; mt < 2; ++mt) {
#pragma unroll
            for (int i = 0; i < 4; ++i) {
                int prow = p0w + mt * 16 + q * 4 + i;
                y[(P0 + prow) * 256 + o] = acc[mt][nt][i] + bo;
            }
        }
    }
}

// ---------------------------------------------------------------------------
// 6) per-channel stats over y [P][256]: sum/sumsq via per-block reduce + atomics
// blocks: 512 (64 pixels each), 256 thr (one per channel)
__global__ void k_stats(const float* __restrict__ y,
                        float* __restrict__ sum, float* __restrict__ sumsq) {
    int o = threadIdx.x;
    int Pb = blockIdx.x * 64;
    float s = 0.f, ss = 0.f;
#pragma unroll 4
    for (int p = 0; p < 64; ++p) {
        float v = y[(Pb + p) * 256 + o];
        s += v; ss += v * v;
    }
    atomicAdd(&sum[o], s);
    atomicAdd(&sumsq[o], ss);
}

// 7) scale/shift per channel
__global__ void k_scale(const float* __restrict__ sum, const float* __restrict__ sumsq,
                        const float* __restrict__ gamma, const float* __restrict__ beta,
                        float* __restrict__ scale, float* __restrict__ shift) {
    int o = threadIdx.x;
    const float n = 32768.f;
    float mean = sum[o] / n;
    float var = sumsq[o] / n - mean * mean;
    float inv = rsqrtf(var + 1e-5f);
    float sc = gamma[o] * inv;
    scale[o] = sc;
    shift[o] = beta[o] - mean * sc;
}

// ---------------------------------------------------------------------------
// 8) BN + ReLU + transpose: y [b,hw,o] -> out [b,o,hw]
// blocks: 8b * 4 otile * 64 hwtile = 2048, 256 thr, 64x64 LDS tile
__global__ void k_bnrelu(const float* __restrict__ y,
                         const float* __restrict__ scale, const float* __restrict__ shift,
                         float* __restrict__ out) {
    int blk = blockIdx.x;
    int hwt = blk & 63;
    int ot  = (blk >> 6) & 3;
    int b   = blk >> 8;
    int hw0 = hwt * 64, o0 = ot * 64;
    __shared__ float tile[64][65];
    int t = threadIdx.x;
#pragma unroll
    for (int r = 0; r < 16; ++r) {
        int idx = t + r * 256;
        int i = idx >> 6, j = idx & 63;   // i: hw row, j: o
        tile[i][j] = y[(b * 4096 + hw0 + i) * 256 + o0 + j];
    }
    __syncthreads();
#pragma unroll
    for (int r = 0; r < 16; ++r) {
        int idx = t + r * 256;
        int j2 = idx >> 6, i2 = idx & 63; // j2: o row, i2: hw
        float v = tile[i2][j2] * scale[o0 + j2] + shift[o0 + j2];
        out[(b * 256 + o0 + j2) * 4096 + hw0 + i2] = fmaxf(v, 0.f);
    }
}

// ---------------------------------------------------------------------------
extern "C" void kernel_launch(void* const* d_in, const int* in_sizes, int n_in,
                              void* d_out, int out_size, void* d_ws, size_t ws_size,
                              hipStream_t stream) {
    const float* x      = (const float*)d_in[0];
    const float* w_off  = (const float*)d_in[1];
    const float* b_off  = (const float*)d_in[2];
    const float* weight = (const float*)d_in[3];
    const float* bias   = (const float*)d_in[4];
    const float* gamma  = (const float*)d_in[5];
    const float* beta   = (const float*)d_in[6];

    char* ws = (char*)d_ws;
    // workspace layout (bytes)
    const size_t OFF_XT    = 0;                       // 16,777,216  bf16 xT
    const size_t OFF_WT    = OFF_XT + 16777216;       //  1,179,648  bf16 wT
    const size_t OFF_WOFT  = OFF_WT + 1179648;        //    147,456  bf16 wofT
    const size_t OFF_OM    = OFF_WOFT + 147456;       //  4,194,304  f32 om
    const size_t OFF_Y     = OFF_OM + 4194304;        // 33,554,432  f32 y
    const size_t OFF_SUM   = OFF_Y + 33554432;        //      1,024
    const size_t OFF_SUMSQ = OFF_SUM + 1024;          //      1,024
    const size_t OFF_SC    = OFF_SUMSQ + 1024;        //      1,024
    const size_t OFF_SH    = OFF_SC + 1024;           //      1,024

    unsigned short* xT   = (unsigned short*)(ws + OFF_XT);
    unsigned short* wT   = (unsigned short*)(ws + OFF_WT);
    unsigned short* wofT = (unsigned short*)(ws + OFF_WOFT);
    float* om    = (float*)(ws + OFF_OM);
    float* y     = (float*)(ws + OFF_Y);
    float* sum   = (float*)(ws + OFF_SUM);
    float* sumsq = (float*)(ws + OFF_SUMSQ);
    float* scale = (float*)(ws + OFF_SC);
    float* shift = (float*)(ws + OFF_SH);

    hipMemsetAsync(ws + OFF_SUM, 0, 2048, stream);   // zero sum+sumsq

    k_pack_x   <<<2048, 256, 0, stream>>>(x, xT);
    k_pack_w   <<<2304, 256, 0, stream>>>(weight, wT);
    k_pack_woff<<< 288, 256, 0, stream>>>(w_off, wofT);
    k_offconv  <<< 512, 256, 0, stream>>>(xT, wofT, b_off, om);
    k_main     <<< 512, 256, 0, stream>>>(xT, wT, om, bias, y);
    k_stats    <<< 512, 256, 0, stream>>>(y, sum, sumsq);
    k_scale    <<<   1, 256, 0, stream>>>(sum, sumsq, gamma, beta, scale, shift);
    k_bnrelu   <<<2048, 256, 0, stream>>>(y, scale, shift, (float*)d_out);
}

// Round 2
// 371.173 us; speedup vs baseline: 1.0010x; 1.0010x over previous
//
#include <hip/hip_runtime.h>
#include <cstdint>

// Problem constants
#define BB    8
#define CIN   256
#define COUT  256
#define HH    64
#define WW    64
#define HWSZ  4096
#define NPIX  32768
#define NTAP  9

typedef __attribute__((ext_vector_type(8))) short    s16x8;
typedef __attribute__((ext_vector_type(8))) unsigned short u16x8;
typedef __attribute__((ext_vector_type(4))) unsigned short u16x4;
typedef __attribute__((ext_vector_type(4))) float    f32x4;

__device__ __forceinline__ float bf2f(unsigned short u) {
    unsigned int v = ((unsigned int)u) << 16;
    return __builtin_bit_cast(float, v);
}
__device__ __forceinline__ unsigned short f2bf(float f) {
    unsigned int u = __builtin_bit_cast(unsigned int, f);
    unsigned int r = (u + 0x7FFFu + ((u >> 16) & 1u)) >> 16;   // RNE
    return (unsigned short)r;
}

// ---------------------------------------------------------------------------
// 1) x [B,C,H,W] fp32 -> xT [B,H,W,C] bf16
__global__ void k_pack_x(const float* __restrict__ x, unsigned short* __restrict__ xT) {
    int blk = blockIdx.x;
    int c0 = (blk & 3) * 64;
    int h  = (blk >> 2) & 63;
    int b  = blk >> 8;
    __shared__ float tile[64][65];
    int t = threadIdx.x;
#pragma unroll
    for (int r = 0; r < 16; ++r) {
        int idx = t + r * 256;
        int i = idx >> 6, w = idx & 63;
        tile[i][w] = x[(((b * 256 + c0 + i) * 64 + h) * 64) + w];
    }
    __syncthreads();
#pragma unroll
    for (int r = 0; r < 16; ++r) {
        int idx = t + r * 256;
        int w = idx >> 6, c = idx & 63;
        xT[((b * 64 + h) * 64 + w) * 256 + c0 + c] = f2bf(tile[c][w]);
    }
}

// 2) weight [O,C,3,3] fp32 -> wT [tap][o][c] bf16
__global__ void k_pack_w(const float* __restrict__ w, unsigned short* __restrict__ wT) {
    int idx = blockIdx.x * 256 + threadIdx.x;
    int c  = idx & 255;
    int o  = (idx >> 8) & 255;
    int tp = idx >> 16;
    wT[idx] = f2bf(w[(o * 256 + c) * 9 + tp]);
}

// 3) w_off [27,C,3,3] fp32 -> wofT [tap][j(32,pad0)][c] bf16
__global__ void k_pack_woff(const float* __restrict__ w, unsigned short* __restrict__ wT) {
    int idx = blockIdx.x * 256 + threadIdx.x;
    int c  = idx & 255;
    int j  = (idx >> 8) & 31;
    int tp = idx >> 13;
    float v = (j < 27) ? w[(j * 256 + c) * 9 + tp] : 0.f;
    wT[idx] = f2bf(v);
}

// ---------------------------------------------------------------------------
// 4) offset conv: om[P][32] = conv(x, w_off)+b_off (raw, no sigmoid)
// 512 blocks (one per (b,h)); 256 thr = 4 waves; wave = 16 px x 32 j
// Stages the 3-row zero-padded neighborhood once per 128-ch chunk:
// only 4 barriers total, 72 MFMAs between barriers.
__global__ __launch_bounds__(256, 2)
void k_offconv(const unsigned short* __restrict__ xT,
               const unsigned short* __restrict__ wofT,
               const float* __restrict__ b_off,
               float* __restrict__ om) {
    int blk = blockIdx.x;
    int b = blk >> 6, h = blk & 63;
    int P0 = blk * 64;
    int t = threadIdx.x;
    int lane = t & 63, wv = t >> 6;
    int p0w = wv * 16;
    int lm = lane & 15, q = lane >> 4;
    __shared__ unsigned short S3[3 * 66 * 136];   // [row][w+pad2][c128+pad8]

    const f32x4 FZ = {0.f, 0.f, 0.f, 0.f};
    f32x4 acc0 = FZ, acc1 = FZ;

    for (int cc = 0; cc < 2; ++cc) {
        __syncthreads();
        if (t < 96) {   // zero the w=0 / w=65 pad columns
            int rr = t >> 5, col = (t >> 4) & 1, c8 = (t & 15) * 8;
            u16x8 z = {0,0,0,0,0,0,0,0};
            *reinterpret_cast<u16x8*>(&S3[(rr * 66 + col * 65) * 136 + c8]) = z;
        }
#pragma unroll
        for (int r = 0; r < 12; ++r) {
            int v = t + r * 256;             // vec8 index over 3*64*16
            int rr = v >> 10, rem = v & 1023;
            int w = rem >> 4, c8 = (rem & 15) * 8;
            int hr = h + rr - 1;
            u16x8 d = {0,0,0,0,0,0,0,0};
            if (hr >= 0 && hr < 64)
                d = *reinterpret_cast<const u16x8*>(xT + ((b * 64 + hr) * 64 + w) * 256 + cc * 128 + c8);
            *reinterpret_cast<u16x8*>(&S3[(rr * 66 + w + 1) * 136 + c8]) = d;
        }
        __syncthreads();
#pragma unroll
        for (int tp = 0; tp < 9; ++tp) {
            int dh = tp / 3, dw = tp % 3;
            const unsigned short* wb = wofT + (tp * 32 + lm) * 256 + cc * 128;
#pragma unroll
            for (int kc = 0; kc < 4; ++kc) {
                s16x8 a = *reinterpret_cast<const s16x8*>(&S3[(dh * 66 + p0w + lm + dw) * 136 + kc * 32 + q * 8]);
                s16x8 b0 = *reinterpret_cast<const s16x8*>(wb + kc * 32 + q * 8);
                s16x8 b1 = *reinterpret_cast<const s16x8*>(wb + 16 * 256 + kc * 32 + q * 8);
                acc0 = __builtin_amdgcn_mfma_f32_16x16x32_bf16(a, b0, acc0, 0, 0, 0);
                acc1 = __builtin_amdgcn_mfma_f32_16x16x32_bf16(a, b1, acc1, 0, 0, 0);
            }
        }
    }
#pragma unroll
    for (int n = 0; n < 2; ++n) {
        int j = n * 16 + lm;
        float bj = (j < 27) ? b_off[j] : 0.f;
        f32x4 a = n ? acc1 : acc0;
#pragma unroll
        for (int i = 0; i < 4; ++i) {
            int prow = p0w + q * 4 + i;
            om[(P0 + prow) * 32 + j] = a[i] + bj;
        }
    }
}

// ---------------------------------------------------------------------------
// 5) main deform GEMM + fused stats; y stored bf16 in MFMA-tile layout
// 512 blocks (one per (b,h)); 512 thr = 8 waves; wave = 32 px x 64 o
// Full-tap staging: 2 barriers per tap (18 total), 64 MFMAs/wave between.
__global__ __launch_bounds__(512, 4)
void k_main(const unsigned short* __restrict__ xT,
            const unsigned short* __restrict__ wT,
            const float* __restrict__ om,
            const float* __restrict__ bias,
            unsigned short* __restrict__ y16,
            float* __restrict__ gsum, float* __restrict__ gssq) {
    int blk = blockIdx.x;
    int b = blk >> 6, h = blk & 63;
    int P0 = blk * 64;
    int t = threadIdx.x;
    int lane = t & 63, wv = t >> 6;
    int ptile = (wv >> 2) * 32;       // 2 pixel tiles of 32
    int o0    = (wv & 3) * 64;        // 4 output tiles of 64
    int lm = lane & 15, q = lane >> 4;

    __shared__ unsigned short S[64 * 264];   // sampled tap tile, padded (+8)
    __shared__ float OM[64 * 33];            // om tile, padded (+1)
    __shared__ float sumbuf[256];
    __shared__ float ssqbuf[256];

    // preload om tile (coalesced) + zero stats buffers
    {
        int v = t * 4;
        int p = v >> 5, j = v & 31;
        float4 tmp = *reinterpret_cast<const float4*>(om + (P0 + p) * 32 + j);
        OM[p * 33 + j]     = tmp.x;
        OM[p * 33 + j + 1] = tmp.y;
        OM[p * 33 + j + 2] = tmp.z;
        OM[p * 33 + j + 3] = tmp.w;
        if (t < 256) sumbuf[t] = 0.f; else ssqbuf[t - 256] = 0.f;
    }

    const f32x4 FZ = {0.f, 0.f, 0.f, 0.f};
    f32x4 acc[2][4];
#pragma unroll
    for (int m = 0; m < 2; ++m)
#pragma unroll
        for (int n = 0; n < 4; ++n) acc[m][n] = FZ;

    int p_s = lane;        // staging pixel (one per lane)
    int kq  = wv;          // staging channel slab [kq*32, kq*32+32)

    for (int tp = 0; tp < 9; ++tp) {
        __syncthreads();   // S readers of prev tap done; OM ready on tp=0
        // bilinear setup for this lane's pixel
        float oh = OM[p_s * 33 + 2 * tp];
        float ow = OM[p_s * 33 + 2 * tp + 1];
        float mv = OM[p_s * 33 + 18 + tp];
        float mk = 1.f / (1.f + __expf(-mv));
        float ph = (float)(h + tp / 3 - 1) + oh;
        float pw = (float)(p_s + tp % 3 - 1) + ow;
        float fh0 = floorf(ph), fw0 = floorf(pw);
        int ih0 = (int)fh0, iw0 = (int)fw0;
        float lh = ph - fh0, lw = pw - fw0;
        float hh = 1.f - lh, hw_ = 1.f - lw;
        bool vh0 = (ih0 >= 0) & (ih0 < 64);
        bool vh1 = (ih0 + 1 >= 0) & (ih0 + 1 < 64);
        bool vw0 = (iw0 >= 0) & (iw0 < 64);
        bool vw1 = (iw0 + 1 >= 0) & (iw0 + 1 < 64);
        float w00 = hh * hw_ * mk * (float)(vh0 & vw0);
        float w01 = hh * lw  * mk * (float)(vh0 & vw1);
        float w10 = lh * hw_ * mk * (float)(vh1 & vw0);
        float w11 = lh * lw  * mk * (float)(vh1 & vw1);
        int ch0 = min(max(ih0, 0), 63), ch1 = min(max(ih0 + 1, 0), 63);
        int cw0 = min(max(iw0, 0), 63), cw1 = min(max(iw0 + 1, 0), 63);
        int rb = b * 4096;
        int a00 = ((rb + ch0 * 64 + cw0) * 256) + kq * 32;
        int a01 = ((rb + ch0 * 64 + cw1) * 256) + kq * 32;
        int a10 = ((rb + ch1 * 64 + cw0) * 256) + kq * 32;
        int a11 = ((rb + ch1 * 64 + cw1) * 256) + kq * 32;

#pragma unroll
        for (int g = 0; g < 4; ++g) {
            int co = g * 8;
            u16x8 r00 = *reinterpret_cast<const u16x8*>(xT + a00 + co);
            u16x8 r01 = *reinterpret_cast<const u16x8*>(xT + a01 + co);
            u16x8 r10 = *reinterpret_cast<const u16x8*>(xT + a10 + co);
            u16x8 r11 = *reinterpret_cast<const u16x8*>(xT + a11 + co);
            u16x8 res;
#pragma unroll
            for (int j = 0; j < 8; ++j) {
                float v = w00 * bf2f(r00[j]);
                v = fmaf(w01, bf2f(r01[j]), v);
                v = fmaf(w10, bf2f(r10[j]), v);
                v = fmaf(w11, bf2f(r11[j]), v);
                res[j] = f2bf(v);
            }
            *reinterpret_cast<u16x8*>(&S[p_s * 264 + kq * 32 + co]) = res;
        }
        __syncthreads();

        const unsigned short* wtap = wT + tp * 65536 + (o0 + lm) * 256 + q * 8;
#pragma unroll
        for (int kc = 0; kc < 8; ++kc) {
            s16x8 a0 = *reinterpret_cast<const s16x8*>(&S[(ptile + lm) * 264 + kc * 32 + q * 8]);
            s16x8 a1 = *reinterpret_cast<const s16x8*>(&S[(ptile + 16 + lm) * 264 + kc * 32 + q * 8]);
#pragma unroll
            for (int nt = 0; nt < 4; ++nt) {
                s16x8 bf = *reinterpret_cast<const s16x8*>(wtap + nt * 4096 + kc * 32);
                acc[0][nt] = __builtin_amdgcn_mfma_f32_16x16x32_bf16(a0, bf, acc[0][nt], 0, 0, 0);
                acc[1][nt] = __builtin_amdgcn_mfma_f32_16x16x32_bf16(a1, bf, acc[1][nt], 0, 0, 0);
            }
        }
    }

    // epilogue: y (bf16, tile layout) + fused stats
    u16x4* yv = reinterpret_cast<u16x4*>(y16);
#pragma unroll
    for (int nt = 0; nt < 4; ++nt) {
        int o = o0 + nt * 16 + lm;
        float bo = bias[o];
        float s = 0.f, ss = 0.f;
#pragma unroll
        for (int mt = 0; mt < 2; ++mt) {
            u16x4 st;
#pragma unroll
            for (int i = 0; i < 4; ++i) {
                float v = acc[mt][nt][i] + bo;
                st[i] = f2bf(v);
                s += v; ss += v * v;
            }
            int idx4 = (((blk * 8 + wv) * 4 + nt) * 2 + mt) * 64 + lane;
            yv[idx4] = st;
        }
        atomicAdd(&sumbuf[o], s);
        atomicAdd(&ssqbuf[o], ss);
    }
    __syncthreads();
    if (t < 256) atomicAdd(&gsum[t], sumbuf[t]);
    else         atomicAdd(&gssq[t - 256], ssqbuf[t - 256]);
}

// ---------------------------------------------------------------------------
// 6) scale/shift per channel
__global__ void k_scale(const float* __restrict__ sum, const float* __restrict__ sumsq,
                        const float* __restrict__ gamma, const float* __restrict__ beta,
                        float* __restrict__ scale, float* __restrict__ shift) {
    int o = threadIdx.x;
    const float n = 32768.f;
    float mean = sum[o] / n;
    float var = sumsq[o] / n - mean * mean;
    float inv = rsqrtf(var + 1e-5f);
    float sc = gamma[o] * inv;
    scale[o] = sc;
    shift[o] = beta[o] - mean * sc;
}

// ---------------------------------------------------------------------------
// 7) BN + ReLU + untile + transpose: y16 tile-layout -> out [b,o,hw] fp32
// 512 blocks (one per main block = (b,h)); 256 thr
__global__ void k_bnrelu(const unsigned short* __restrict__ y16,
                         const float* __restrict__ scale, const float* __restrict__ shift,
                         float* __restrict__ out) {
    int blk = blockIdx.x;
    int b = blk >> 6, h = blk & 63;
    __shared__ unsigned short T[64 * 257];
    int t = threadIdx.x;
    const u16x4* yv = reinterpret_cast<const u16x4*>(y16) + blk * 4096;
#pragma unroll
    for (int r = 0; r < 16; ++r) {
        int v = t + r * 256;
        u16x4 d = yv[v];
        int lane = v & 63, mt = (v >> 6) & 1, nt = (v >> 7) & 3, wvv = v >> 9;
        int p = (wvv >> 2) * 32 + mt * 16 + (lane >> 4) * 4;
        int o = (wvv & 3) * 64 + nt * 16 + (lane & 15);
        T[(p + 0) * 257 + o] = d[0];
        T[(p + 1) * 257 + o] = d[1];
        T[(p + 2) * 257 + o] = d[2];
        T[(p + 3) * 257 + o] = d[3];
    }
    __syncthreads();
    int w = t & 63;
    int ob = (t >> 6) * 64;
    float* obase = out + (size_t)b * (256 * 4096) + h * 64 + w;
#pragma unroll 4
    for (int rr = 0; rr < 64; ++rr) {
        int o = ob + rr;
        float v = bf2f(T[w * 257 + o]);
        obase[(size_t)o * 4096] = fmaxf(v * scale[o] + shift[o], 0.f);
    }
}

// ---------------------------------------------------------------------------
extern "C" void kernel_launch(void* const* d_in, const int* in_sizes, int n_in,
                              void* d_out, int out_size, void* d_ws, size_t ws_size,
                              hipStream_t stream) {
    const float* x      = (const float*)d_in[0];
    const float* w_off  = (const float*)d_in[1];
    const float* b_off  = (const float*)d_in[2];
    const float* weight = (const float*)d_in[3];
    const float* bias   = (const float*)d_in[4];
    const float* gamma  = (const float*)d_in[5];
    const float* beta   = (const float*)d_in[6];

    char* ws = (char*)d_ws;
    const size_t OFF_XT    = 0;                       // 16,777,216  bf16 xT
    const size_t OFF_WT    = OFF_XT + 16777216;       //  1,179,648  bf16 wT
    const size_t OFF_WOFT  = OFF_WT + 1179648;        //    147,456  bf16 wofT
    const size_t OFF_OM    = OFF_WOFT + 147456;       //  4,194,304  f32 om
    const size_t OFF_Y16   = OFF_OM + 4194304;        // 16,777,216  bf16 y tile-layout
    const size_t OFF_SUM   = OFF_Y16 + 16777216;      //      1,024
    const size_t OFF_SUMSQ = OFF_SUM + 1024;
    const size_t OFF_SC    = OFF_SUMSQ + 1024;
    const size_t OFF_SH    = OFF_SC + 1024;

    unsigned short* xT   = (unsigned short*)(ws + OFF_XT);
    unsigned short* wT   = (unsigned short*)(ws + OFF_WT);
    unsigned short* wofT = (unsigned short*)(ws + OFF_WOFT);
    float* om    = (float*)(ws + OFF_OM);
    unsigned short* y16  = (unsigned short*)(ws + OFF_Y16);
    float* sum   = (float*)(ws + OFF_SUM);
    float* sumsq = (float*)(ws + OFF_SUMSQ);
    float* scale = (float*)(ws + OFF_SC);
    float* shift = (float*)(ws + OFF_SH);

    hipMemsetAsync(ws + OFF_SUM, 0, 2048, stream);

    k_pack_x   <<<2048, 256, 0, stream>>>(x, xT);
    k_pack_w   <<<2304, 256, 0, stream>>>(weight, wT);
    k_pack_woff<<< 288, 256, 0, stream>>>(w_off, wofT);
    k_offconv  <<< 512, 256, 0, stream>>>(xT, wofT, b_off, om);
    k_main     <<< 512, 512, 0, stream>>>(xT, wT, om, bias, y16, sum, sumsq);
    k_scale    <<<   1, 256, 0, stream>>>(sum, sumsq, gamma, beta, scale, shift);
    k_bnrelu   <<< 512, 256, 0, stream>>>(y16, scale, shift, (float*)d_out);
}

// Round 4
// 242.023 us; speedup vs baseline: 1.5351x; 1.5336x over previous
//
#include <hip/hip_runtime.h>
#include <cstdint>

#define BB    8
#define CIN   256
#define COUT  256
#define HH    64
#define WW    64
#define HWSZ  4096
#define NPIX  32768
#define NTAP  9

typedef __attribute__((ext_vector_type(8))) short    s16x8;
typedef __attribute__((ext_vector_type(8))) unsigned short u16x8;
typedef __attribute__((ext_vector_type(4))) unsigned short u16x4;
typedef __attribute__((ext_vector_type(4))) float    f32x4;

__device__ __forceinline__ float bf2f(unsigned short u) {
    unsigned int v = ((unsigned int)u) << 16;
    return __builtin_bit_cast(float, v);
}
__device__ __forceinline__ unsigned short f2bf(float f) {
    unsigned int u = __builtin_bit_cast(unsigned int, f);
    unsigned int r = (u + 0x7FFFu + ((u >> 16) & 1u)) >> 16;   // RNE
    return (unsigned short)r;
}

// ---------------------------------------------------------------------------
// 1) x [B,C,H,W] fp32 -> xT [B,H,W,C] bf16
__global__ void k_pack_x(const float* __restrict__ x, unsigned short* __restrict__ xT) {
    int blk = blockIdx.x;
    int c0 = (blk & 3) * 64;
    int h  = (blk >> 2) & 63;
    int b  = blk >> 8;
    __shared__ float tile[64][65];
    int t = threadIdx.x;
#pragma unroll
    for (int r = 0; r < 16; ++r) {
        int idx = t + r * 256;
        int i = idx >> 6, w = idx & 63;
        tile[i][w] = x[(((b * 256 + c0 + i) * 64 + h) * 64) + w];
    }
    __syncthreads();
#pragma unroll
    for (int r = 0; r < 16; ++r) {
        int idx = t + r * 256;
        int w = idx >> 6, c = idx & 63;
        xT[((b * 64 + h) * 64 + w) * 256 + c0 + c] = f2bf(tile[c][w]);
    }
}

// 2) weight [O,C,3,3] fp32 -> wTk[tap][kc8][n16][o16][q4][j8] bf16 (589,824 elems)
// Per-tap stride 65536 u16. B-frag for (tap,kc,ntile): 1KB contiguous;
// lane(lm,q) reads offset o16=lm *32 + q*8.
__global__ void k_pack_wk(const float* __restrict__ w, unsigned short* __restrict__ wT) {
    int idx = blockIdx.x * 256 + threadIdx.x;   // 0 .. 589,823
    int j   = idx & 7;
    int q   = (idx >> 3) & 3;
    int o16 = (idx >> 5) & 15;
    int n16 = (idx >> 9) & 15;
    int kc  = (idx >> 13) & 7;
    int tp  = idx >> 16;                        // 0..8
    int c = kc * 32 + q * 8 + j;
    int o = n16 * 16 + o16;
    wT[idx] = f2bf(w[(o * 256 + c) * 9 + tp]);
}

// 3) w_off [27,C,3,3] fp32 -> wofT [tap][j(32,pad0)][c] bf16
__global__ void k_pack_woff(const float* __restrict__ w, unsigned short* __restrict__ wT) {
    int idx = blockIdx.x * 256 + threadIdx.x;
    int c  = idx & 255;
    int j  = (idx >> 8) & 31;
    int tp = idx >> 13;
    float v = (j < 27) ? w[(j * 256 + c) * 9 + tp] : 0.f;
    wT[idx] = f2bf(v);
}

// ---------------------------------------------------------------------------
// 4) offset conv: om[P][32] = conv(x, w_off)+b_off (raw, no sigmoid)
__global__ __launch_bounds__(256, 2)
void k_offconv(const unsigned short* __restrict__ xT,
               const unsigned short* __restrict__ wofT,
               const float* __restrict__ b_off,
               float* __restrict__ om) {
    int blk = blockIdx.x;
    int b = blk >> 6, h = blk & 63;
    int P0 = blk * 64;
    int t = threadIdx.x;
    int lane = t & 63, wv = t >> 6;
    int p0w = wv * 16;
    int lm = lane & 15, q = lane >> 4;
    __shared__ unsigned short S3[3 * 66 * 136];   // [row][w+pad2][c128+pad8]

    const f32x4 FZ = {0.f, 0.f, 0.f, 0.f};
    f32x4 acc0 = FZ, acc1 = FZ;

    for (int cc = 0; cc < 2; ++cc) {
        __syncthreads();
        if (t < 96) {   // zero the w=0 / w=65 pad columns
            int rr = t >> 5, col = (t >> 4) & 1, c8 = (t & 15) * 8;
            u16x8 z = {0,0,0,0,0,0,0,0};
            *reinterpret_cast<u16x8*>(&S3[(rr * 66 + col * 65) * 136 + c8]) = z;
        }
#pragma unroll
        for (int r = 0; r < 12; ++r) {
            int v = t + r * 256;
            int rr = v >> 10, rem = v & 1023;
            int w = rem >> 4, c8 = (rem & 15) * 8;
            int hr = h + rr - 1;
            u16x8 d = {0,0,0,0,0,0,0,0};
            if (hr >= 0 && hr < 64)
                d = *reinterpret_cast<const u16x8*>(xT + ((b * 64 + hr) * 64 + w) * 256 + cc * 128 + c8);
            *reinterpret_cast<u16x8*>(&S3[(rr * 66 + w + 1) * 136 + c8]) = d;
        }
        __syncthreads();
#pragma unroll
        for (int tp = 0; tp < 9; ++tp) {
            int dh = tp / 3, dw = tp % 3;
            const unsigned short* wb = wofT + (tp * 32 + lm) * 256 + cc * 128;
#pragma unroll
            for (int kc = 0; kc < 4; ++kc) {
                s16x8 a = *reinterpret_cast<const s16x8*>(&S3[(dh * 66 + p0w + lm + dw) * 136 + kc * 32 + q * 8]);
                s16x8 b0 = *reinterpret_cast<const s16x8*>(wb + kc * 32 + q * 8);
                s16x8 b1 = *reinterpret_cast<const s16x8*>(wb + 16 * 256 + kc * 32 + q * 8);
                acc0 = __builtin_amdgcn_mfma_f32_16x16x32_bf16(a, b0, acc0, 0, 0, 0);
                acc1 = __builtin_amdgcn_mfma_f32_16x16x32_bf16(a, b1, acc1, 0, 0, 0);
            }
        }
    }
#pragma unroll
    for (int n = 0; n < 2; ++n) {
        int j = n * 16 + lm;
        float bj = (j < 27) ? b_off[j] : 0.f;
        f32x4 a = n ? acc1 : acc0;
#pragma unroll
        for (int i = 0; i < 4; ++i) {
            int prow = p0w + q * 4 + i;
            om[(P0 + prow) * 32 + j] = a[i] + bj;
        }
    }
}

// ---------------------------------------------------------------------------
// 5) main deform GEMM + fused stats; y stored bf16 in MFMA-tile layout
// 512 blocks (one per (b,h)); 512 thr = 8 waves.
// Staging: 8 lanes per pixel -> each gather inst = 8 px x 128B contig = 16 lines.
// MFMA: wave = 64 px x 32 o (8 waves = 256 o, no B duplication);
//       B-frags read 1KB-contiguous from wTk (16 lines/inst).
__global__ __launch_bounds__(512, 4)
void k_main(const unsigned short* __restrict__ xT,
            const unsigned short* __restrict__ wTk,
            const float* __restrict__ om,
            const float* __restrict__ bias,
            unsigned short* __restrict__ y16,
            float* __restrict__ gsum, float* __restrict__ gssq) {
    int blk = blockIdx.x;
    int b = blk >> 6, h = blk & 63;
    int P0 = blk * 64;
    int t = threadIdx.x;
    int lane = t & 63, wv = t >> 6;
    int lm = lane & 15, q = lane >> 4;
    int o0 = wv * 32;                       // wave o-tile

    __shared__ unsigned short S[64 * 264];  // sampled tap tile (stride 132 dw: 2-way max)
    __shared__ float sumbuf[256];
    __shared__ float ssqbuf[256];
    if (t < 256) sumbuf[t] = 0.f; else ssqbuf[t - 256] = 0.f;

    const f32x4 FZ = {0.f, 0.f, 0.f, 0.f};
    f32x4 acc[4][2];
#pragma unroll
    for (int m = 0; m < 4; ++m)
#pragma unroll
        for (int n = 0; n < 2; ++n) acc[m][n] = FZ;

    int p  = wv * 8 + (lane >> 3);          // staging pixel (8 lanes each)
    int s  = lane & 7;                      // 16B sub-chunk
    int P  = P0 + p;
    int rb = b * 4096;

    for (int tp = 0; tp < 9; ++tp) {
        // bilinear setup (8 lanes per pixel compute identically; om loads broadcast)
        float oh = om[P * 32 + 2 * tp];
        float ow = om[P * 32 + 2 * tp + 1];
        float mv = om[P * 32 + 18 + tp];
        float mk = 1.f / (1.f + __expf(-mv));
        float ph = (float)(h + tp / 3 - 1) + oh;
        float pw = (float)(p + tp % 3 - 1) + ow;
        float fh0 = floorf(ph), fw0 = floorf(pw);
        int ih0 = (int)fh0, iw0 = (int)fw0;
        float lh = ph - fh0, lw = pw - fw0;
        float hh = 1.f - lh, hw_ = 1.f - lw;
        bool vh0 = (ih0 >= 0) & (ih0 < 64);
        bool vh1 = (ih0 + 1 >= 0) & (ih0 + 1 < 64);
        bool vw0 = (iw0 >= 0) & (iw0 < 64);
        bool vw1 = (iw0 + 1 >= 0) & (iw0 + 1 < 64);
        float w00 = hh * hw_ * mk * (float)(vh0 & vw0);
        float w01 = hh * lw  * mk * (float)(vh0 & vw1);
        float w10 = lh * hw_ * mk * (float)(vh1 & vw0);
        float w11 = lh * lw  * mk * (float)(vh1 & vw1);
        int ch0 = min(max(ih0, 0), 63), ch1 = min(max(ih0 + 1, 0), 63);
        int cw0 = min(max(iw0, 0), 63), cw1 = min(max(iw0 + 1, 0), 63);
        int a00 = ((rb + ch0 * 64 + cw0) * 256) + s * 8;
        int a01 = ((rb + ch0 * 64 + cw1) * 256) + s * 8;
        int a10 = ((rb + ch1 * 64 + cw0) * 256) + s * 8;
        int a11 = ((rb + ch1 * 64 + cw1) * 256) + s * 8;

        __syncthreads();   // prev-tap MFMA reads of S complete
#pragma unroll
        for (int j = 0; j < 4; ++j) {
            u16x8 r00 = *reinterpret_cast<const u16x8*>(xT + a00 + j * 64);
            u16x8 r01 = *reinterpret_cast<const u16x8*>(xT + a01 + j * 64);
            u16x8 r10 = *reinterpret_cast<const u16x8*>(xT + a10 + j * 64);
            u16x8 r11 = *reinterpret_cast<const u16x8*>(xT + a11 + j * 64);
            u16x8 res;
#pragma unroll
            for (int k = 0; k < 8; ++k) {
                float v = w00 * bf2f(r00[k]);
                v = fmaf(w01, bf2f(r01[k]), v);
                v = fmaf(w10, bf2f(r10[k]), v);
                v = fmaf(w11, bf2f(r11[k]), v);
                res[k] = f2bf(v);
            }
            *reinterpret_cast<u16x8*>(&S[p * 264 + j * 64 + s * 8]) = res;
        }
        __syncthreads();

        // MFMA: wave = 64 px x 32 o
        const unsigned short* wtap = wTk + (size_t)tp * 65536 + (size_t)(wv * 2) * 512
                                   + lm * 32 + q * 8;
#pragma unroll
        for (int kc = 0; kc < 8; ++kc) {
            const unsigned short* wb = wtap + kc * 8192;
            s16x8 b0 = *reinterpret_cast<const s16x8*>(wb);
            s16x8 b1 = *reinterpret_cast<const s16x8*>(wb + 512);
#pragma unroll
            for (int mt = 0; mt < 4; ++mt) {
                s16x8 a = *reinterpret_cast<const s16x8*>(&S[(mt * 16 + lm) * 264 + kc * 32 + q * 8]);
                acc[mt][0] = __builtin_amdgcn_mfma_f32_16x16x32_bf16(a, b0, acc[mt][0], 0, 0, 0);
                acc[mt][1] = __builtin_amdgcn_mfma_f32_16x16x32_bf16(a, b1, acc[mt][1], 0, 0, 0);
            }
        }
    }

    // epilogue: y (bf16, tile layout) + fused stats
    u16x4* yv = reinterpret_cast<u16x4*>(y16);
#pragma unroll
    for (int nt = 0; nt < 2; ++nt) {
        int o = o0 + nt * 16 + lm;
        float bo = bias[o];
        float sacc = 0.f, ssacc = 0.f;
#pragma unroll
        for (int mt = 0; mt < 4; ++mt) {
            u16x4 st;
#pragma unroll
            for (int i = 0; i < 4; ++i) {
                float v = acc[mt][nt][i] + bo;
                st[i] = f2bf(v);
                sacc += v; ssacc += v * v;
            }
            int idx4 = (((blk * 8 + wv) * 2 + nt) * 4 + mt) * 64 + lane;
            yv[idx4] = st;
        }
        atomicAdd(&sumbuf[o], sacc);
        atomicAdd(&ssqbuf[o], ssacc);
    }
    __syncthreads();
    if (t < 256) atomicAdd(&gsum[t], sumbuf[t]);
    else         atomicAdd(&gssq[t - 256], ssqbuf[t - 256]);
}

// ---------------------------------------------------------------------------
// 6) BN + ReLU + untile + transpose (scale/shift computed in-block from gsum/gssq)
__global__ void k_bnrelu(const unsigned short* __restrict__ y16,
                         const float* __restrict__ gsum, const float* __restrict__ gssq,
                         const float* __restrict__ gamma, const float* __restrict__ beta,
                         float* __restrict__ out) {
    int blk = blockIdx.x;
    int b = blk >> 6, h = blk & 63;
    __shared__ unsigned short T[64 * 257];
    __shared__ float sc[256], sh[256];
    int t = threadIdx.x;
    {   // per-channel scale/shift (redundant per block; trivial)
        const float n = 32768.f;
        float mean = gsum[t] / n;
        float var = gssq[t] / n - mean * mean;
        float inv = rsqrtf(var + 1e-5f);
        float s = gamma[t] * inv;
        sc[t] = s;
        sh[t] = beta[t] - mean * s;
    }
    const u16x4* yv = reinterpret_cast<const u16x4*>(y16) + blk * 4096;
#pragma unroll
    for (int r = 0; r < 16; ++r) {
        int v = t + r * 256;
        u16x4 d = yv[v];
        int lane = v & 63, mt = (v >> 6) & 3, nt = (v >> 8) & 1, wvv = (v >> 9) & 7;
        int p = mt * 16 + (lane >> 4) * 4;
        int o = wvv * 32 + nt * 16 + (lane & 15);
        T[(p + 0) * 257 + o] = d[0];
        T[(p + 1) * 257 + o] = d[1];
        T[(p + 2) * 257 + o] = d[2];
        T[(p + 3) * 257 + o] = d[3];
    }
    __syncthreads();
    int w = t & 63;
    int ob = (t >> 6) * 64;
    float* obase = out + (size_t)b * (256 * 4096) + h * 64 + w;
#pragma unroll 4
    for (int rr = 0; rr < 64; ++rr) {
        int o = ob + rr;
        float v = bf2f(T[w * 257 + o]);
        obase[(size_t)o * 4096] = fmaxf(v * sc[o] + sh[o], 0.f);
    }
}

// ---------------------------------------------------------------------------
extern "C" void kernel_launch(void* const* d_in, const int* in_sizes, int n_in,
                              void* d_out, int out_size, void* d_ws, size_t ws_size,
                              hipStream_t stream) {
    const float* x      = (const float*)d_in[0];
    const float* w_off  = (const float*)d_in[1];
    const float* b_off  = (const float*)d_in[2];
    const float* weight = (const float*)d_in[3];
    const float* bias   = (const float*)d_in[4];
    const float* gamma  = (const float*)d_in[5];
    const float* beta   = (const float*)d_in[6];

    char* ws = (char*)d_ws;
    const size_t OFF_XT    = 0;                       // 16,777,216  bf16 xT
    const size_t OFF_WT    = OFF_XT + 16777216;       //  1,179,648  bf16 wTk
    const size_t OFF_WOFT  = OFF_WT + 1179648;        //    147,456  bf16 wofT
    const size_t OFF_OM    = OFF_WOFT + 147456;       //  4,194,304  f32 om
    const size_t OFF_Y16   = OFF_OM + 4194304;        // 16,777,216  bf16 y tile-layout
    const size_t OFF_SUM   = OFF_Y16 + 16777216;      //      1,024
    const size_t OFF_SUMSQ = OFF_SUM + 1024;

    unsigned short* xT   = (unsigned short*)(ws + OFF_XT);
    unsigned short* wTk  = (unsigned short*)(ws + OFF_WT);
    unsigned short* wofT = (unsigned short*)(ws + OFF_WOFT);
    float* om    = (float*)(ws + OFF_OM);
    unsigned short* y16  = (unsigned short*)(ws + OFF_Y16);
    float* sum   = (float*)(ws + OFF_SUM);
    float* sumsq = (float*)(ws + OFF_SUMSQ);

    hipMemsetAsync(ws + OFF_SUM, 0, 2048, stream);

    k_pack_x   <<<2048, 256, 0, stream>>>(x, xT);
    k_pack_wk  <<<2304, 256, 0, stream>>>(weight, wTk);
    k_pack_woff<<< 288, 256, 0, stream>>>(w_off, wofT);
    k_offconv  <<< 512, 256, 0, stream>>>(xT, wofT, b_off, om);
    k_main     <<< 512, 512, 0, stream>>>(xT, wTk, om, bias, y16, sum, sumsq);
    k_bnrelu   <<< 512, 256, 0, stream>>>(y16, sum, sumsq, gamma, beta, (float*)d_out);
}

// Round 5
// 227.122 us; speedup vs baseline: 1.6358x; 1.0656x over previous
//
#include <hip/hip_runtime.h>
#include <cstdint>

#define BB    8
#define CIN   256
#define COUT  256
#define HH    64
#define WW    64
#define HWSZ  4096
#define NPIX  32768
#define NTAP  9

typedef __attribute__((ext_vector_type(8))) short    s16x8;
typedef __attribute__((ext_vector_type(8))) unsigned short u16x8;
typedef __attribute__((ext_vector_type(4))) unsigned short u16x4;
typedef __attribute__((ext_vector_type(4))) float    f32x4;

__device__ __forceinline__ float bf2f(unsigned short u) {
    unsigned int v = ((unsigned int)u) << 16;
    return __builtin_bit_cast(float, v);
}
__device__ __forceinline__ unsigned short f2bf(float f) {
    unsigned int u = __builtin_bit_cast(unsigned int, f);
    unsigned int r = (u + 0x7FFFu + ((u >> 16) & 1u)) >> 16;   // RNE
    return (unsigned short)r;
}

// ---------------------------------------------------------------------------
// 1) x [B,C,H,W] fp32 -> xT [B,H,W,C] bf16.  b = blk%8 for XCD affinity:
// xT[b] is produced on the same XCD that later consumes it.
__global__ void k_pack_x(const float* __restrict__ x, unsigned short* __restrict__ xT) {
    int blk = blockIdx.x;
    int b    = blk & 7;
    int rest = blk >> 3;
    int h    = rest >> 2;
    int c0   = (rest & 3) * 64;
    __shared__ float tile[64][65];
    int t = threadIdx.x;
#pragma unroll
    for (int r = 0; r < 16; ++r) {
        int idx = t + r * 256;
        int i = idx >> 6, w = idx & 63;
        tile[i][w] = x[(((b * 256 + c0 + i) * 64 + h) * 64) + w];
    }
    __syncthreads();
#pragma unroll
    for (int r = 0; r < 16; ++r) {
        int idx = t + r * 256;
        int w = idx >> 6, c = idx & 63;
        xT[((b * 64 + h) * 64 + w) * 256 + c0 + c] = f2bf(tile[c][w]);
    }
}

// 2) weight [O,C,3,3] fp32 -> wTk[tap][kc8][n16][o16][q4][j8] bf16 (589,824)
__global__ void k_pack_wk(const float* __restrict__ w, unsigned short* __restrict__ wT) {
    int idx = blockIdx.x * 256 + threadIdx.x;
    int j   = idx & 7;
    int q   = (idx >> 3) & 3;
    int o16 = (idx >> 5) & 15;
    int n16 = (idx >> 9) & 15;
    int kc  = (idx >> 13) & 7;
    int tp  = idx >> 16;
    int c = kc * 32 + q * 8 + j;
    int o = n16 * 16 + o16;
    wT[idx] = f2bf(w[(o * 256 + c) * 9 + tp]);
}

// 3) w_off [27,C,3,3] fp32 -> wofT [tap][j(32,pad0)][c] bf16
__global__ void k_pack_woff(const float* __restrict__ w, unsigned short* __restrict__ wT) {
    int idx = blockIdx.x * 256 + threadIdx.x;
    int c  = idx & 255;
    int j  = (idx >> 8) & 31;
    int tp = idx >> 13;
    float v = (j < 27) ? w[(j * 256 + c) * 9 + tp] : 0.f;
    wT[idx] = f2bf(v);
}

// ---------------------------------------------------------------------------
// 4) offset conv: om[P][32] = conv(x, w_off)+b_off (raw, no sigmoid)
// b = blk%8 XCD affinity.
__global__ __launch_bounds__(256, 2)
void k_offconv(const unsigned short* __restrict__ xT,
               const unsigned short* __restrict__ wofT,
               const float* __restrict__ b_off,
               float* __restrict__ om) {
    int blk = blockIdx.x;
    int b = blk & 7, h = blk >> 3;
    int P0 = (b * 64 + h) * 64;
    int t = threadIdx.x;
    int lane = t & 63, wv = t >> 6;
    int p0w = wv * 16;
    int lm = lane & 15, q = lane >> 4;
    __shared__ unsigned short S3[3 * 66 * 136];   // [row][w+pad2][c128+pad8]

    const f32x4 FZ = {0.f, 0.f, 0.f, 0.f};
    f32x4 acc0 = FZ, acc1 = FZ;

    for (int cc = 0; cc < 2; ++cc) {
        __syncthreads();
        if (t < 96) {   // zero the w=0 / w=65 pad columns
            int rr = t >> 5, col = (t >> 4) & 1, c8 = (t & 15) * 8;
            u16x8 z = {0,0,0,0,0,0,0,0};
            *reinterpret_cast<u16x8*>(&S3[(rr * 66 + col * 65) * 136 + c8]) = z;
        }
#pragma unroll
        for (int r = 0; r < 12; ++r) {
            int v = t + r * 256;
            int rr = v >> 10, rem = v & 1023;
            int w = rem >> 4, c8 = (rem & 15) * 8;
            int hr = h + rr - 1;
            u16x8 d = {0,0,0,0,0,0,0,0};
            if (hr >= 0 && hr < 64)
                d = *reinterpret_cast<const u16x8*>(xT + ((b * 64 + hr) * 64 + w) * 256 + cc * 128 + c8);
            *reinterpret_cast<u16x8*>(&S3[(rr * 66 + w + 1) * 136 + c8]) = d;
        }
        __syncthreads();
#pragma unroll
        for (int tp = 0; tp < 9; ++tp) {
            int dh = tp / 3, dw = tp % 3;
            const unsigned short* wb = wofT + (tp * 32 + lm) * 256 + cc * 128;
#pragma unroll
            for (int kc = 0; kc < 4; ++kc) {
                s16x8 a = *reinterpret_cast<const s16x8*>(&S3[(dh * 66 + p0w + lm + dw) * 136 + kc * 32 + q * 8]);
                s16x8 b0 = *reinterpret_cast<const s16x8*>(wb + kc * 32 + q * 8);
                s16x8 b1 = *reinterpret_cast<const s16x8*>(wb + 16 * 256 + kc * 32 + q * 8);
                acc0 = __builtin_amdgcn_mfma_f32_16x16x32_bf16(a, b0, acc0, 0, 0, 0);
                acc1 = __builtin_amdgcn_mfma_f32_16x16x32_bf16(a, b1, acc1, 0, 0, 0);
            }
        }
    }
#pragma unroll
    for (int n = 0; n < 2; ++n) {
        int j = n * 16 + lm;
        float bj = (j < 27) ? b_off[j] : 0.f;
        f32x4 a = n ? acc1 : acc0;
#pragma unroll
        for (int i = 0; i < 4; ++i) {
            int prow = p0w + q * 4 + i;
            om[(P0 + prow) * 32 + j] = a[i] + bj;
        }
    }
}

// ---------------------------------------------------------------------------
// 5) main deform GEMM + fused stats; y stored bf16 in MFMA-tile layout.
// b = blk%8 XCD affinity (xT[b] + wTk fit in 4MiB per-XCD L2).
// Cross-tap software pipeline: gathers for tap t+1 issued between the barrier
// and the MFMAs of tap t (consumed next iteration, no barrier in between ->
// no vmcnt(0) drain of the prefetch). Double-buffered S.
__global__ __launch_bounds__(512, 2)
void k_main(const unsigned short* __restrict__ xT,
            const unsigned short* __restrict__ wTk,
            const float* __restrict__ om,
            const float* __restrict__ bias,
            unsigned short* __restrict__ y16,
            float* __restrict__ gsum, float* __restrict__ gssq) {
    int blk = blockIdx.x;
    int b = blk & 7, h = blk >> 3;
    int pblk = b * 64 + h;
    int P0 = pblk * 64;
    int t = threadIdx.x;
    int lane = t & 63, wv = t >> 6;
    int lm = lane & 15, q = lane >> 4;
    int o0 = wv * 32;                       // wave o-tile

    __shared__ unsigned short S[2][64 * 264];  // double-buffered sampled tile
    __shared__ float OMS[64 * 32];             // om tile (broadcast reads)

    // preload om tile once (coalesced float4)
    {
        float4 tmp = *reinterpret_cast<const float4*>(om + P0 * 32 + t * 4);
        *reinterpret_cast<float4*>(&OMS[t * 4]) = tmp;
    }
    __syncthreads();

    const f32x4 FZ = {0.f, 0.f, 0.f, 0.f};
    f32x4 acc[4][2];
#pragma unroll
    for (int m = 0; m < 4; ++m)
#pragma unroll
        for (int n = 0; n < 2; ++n) acc[m][n] = FZ;

    int p  = wv * 8 + (lane >> 3);          // staging pixel (8 lanes each)
    int s  = lane & 7;                      // 16B sub-chunk
    int rb = b * 4096;

    float w00, w01, w10, w11;
    int a00, a01, a10, a11;
    u16x8 r00[4], r01[4], r10[4], r11[4];

    // bilinear setup for tap tp (reads OMS, pure VALU)
    auto setup = [&](int tp) {
        float oh = OMS[p * 32 + 2 * tp];
        float ow = OMS[p * 32 + 2 * tp + 1];
        float mv = OMS[p * 32 + 18 + tp];
        float mk = 1.f / (1.f + __expf(-mv));
        float ph = (float)(h + tp / 3 - 1) + oh;
        float pw = (float)(p + tp % 3 - 1) + ow;
        float fh0 = floorf(ph), fw0 = floorf(pw);
        int ih0 = (int)fh0, iw0 = (int)fw0;
        float lh = ph - fh0, lw = pw - fw0;
        float hh = 1.f - lh, hw_ = 1.f - lw;
        bool vh0 = (ih0 >= 0) & (ih0 < 64);
        bool vh1 = (ih0 + 1 >= 0) & (ih0 + 1 < 64);
        bool vw0 = (iw0 >= 0) & (iw0 < 64);
        bool vw1 = (iw0 + 1 >= 0) & (iw0 + 1 < 64);
        w00 = hh * hw_ * mk * (float)(vh0 & vw0);
        w01 = hh * lw  * mk * (float)(vh0 & vw1);
        w10 = lh * hw_ * mk * (float)(vh1 & vw0);
        w11 = lh * lw  * mk * (float)(vh1 & vw1);
        int ch0 = min(max(ih0, 0), 63), ch1 = min(max(ih0 + 1, 0), 63);
        int cw0 = min(max(iw0, 0), 63), cw1 = min(max(iw0 + 1, 0), 63);
        a00 = ((rb + ch0 * 64 + cw0) * 256) + s * 8;
        a01 = ((rb + ch0 * 64 + cw1) * 256) + s * 8;
        a10 = ((rb + ch1 * 64 + cw0) * 256) + s * 8;
        a11 = ((rb + ch1 * 64 + cw1) * 256) + s * 8;
    };
    auto issue = [&]() {
#pragma unroll
        for (int j = 0; j < 4; ++j) {
            r00[j] = *reinterpret_cast<const u16x8*>(xT + a00 + j * 64);
            r01[j] = *reinterpret_cast<const u16x8*>(xT + a01 + j * 64);
            r10[j] = *reinterpret_cast<const u16x8*>(xT + a10 + j * 64);
            r11[j] = *reinterpret_cast<const u16x8*>(xT + a11 + j * 64);
        }
    };

    setup(0);
    issue();

    for (int tp = 0; tp < 9; ++tp) {
        int cur = tp & 1;
        // blend prefetched gathers -> S[cur]
#pragma unroll
        for (int j = 0; j < 4; ++j) {
            u16x8 res;
#pragma unroll
            for (int k = 0; k < 8; ++k) {
                float v = w00 * bf2f(r00[j][k]);
                v = fmaf(w01, bf2f(r01[j][k]), v);
                v = fmaf(w10, bf2f(r10[j][k]), v);
                v = fmaf(w11, bf2f(r11[j][k]), v);
                res[k] = f2bf(v);
            }
            *reinterpret_cast<u16x8*>(&S[cur][p * 264 + j * 64 + s * 8]) = res;
        }
        __syncthreads();

        if (tp < 8) {       // prefetch next tap (in flight across the MFMAs)
            setup(tp + 1);
            issue();
        }

        // MFMA: wave = 64 px x 32 o, reading S[cur]
        const unsigned short* wtap = wTk + (size_t)tp * 65536 + (size_t)(wv * 2) * 512
                                   + lm * 32 + q * 8;
#pragma unroll
        for (int kc = 0; kc < 8; ++kc) {
            const unsigned short* wb = wtap + kc * 8192;
            s16x8 b0 = *reinterpret_cast<const s16x8*>(wb);
            s16x8 b1 = *reinterpret_cast<const s16x8*>(wb + 512);
#pragma unroll
            for (int mt = 0; mt < 4; ++mt) {
                s16x8 a = *reinterpret_cast<const s16x8*>(&S[cur][(mt * 16 + lm) * 264 + kc * 32 + q * 8]);
                acc[mt][0] = __builtin_amdgcn_mfma_f32_16x16x32_bf16(a, b0, acc[mt][0], 0, 0, 0);
                acc[mt][1] = __builtin_amdgcn_mfma_f32_16x16x32_bf16(a, b1, acc[mt][1], 0, 0, 0);
            }
        }
    }

    // epilogue: y (bf16, tile layout) + stats via q-shuffle reduce + global atomics
    u16x4* yv = reinterpret_cast<u16x4*>(y16);
#pragma unroll
    for (int nt = 0; nt < 2; ++nt) {
        int o = o0 + nt * 16 + lm;
        float bo = bias[o];
        float sacc = 0.f, ssacc = 0.f;
#pragma unroll
        for (int mt = 0; mt < 4; ++mt) {
            u16x4 st;
#pragma unroll
            for (int i = 0; i < 4; ++i) {
                float v = acc[mt][nt][i] + bo;
                st[i] = f2bf(v);
                sacc += v; ssacc += v * v;
            }
            int idx4 = (((pblk * 8 + wv) * 2 + nt) * 4 + mt) * 64 + lane;
            yv[idx4] = st;
        }
        // reduce across the 4 q-lanes holding the same o (lanes differ by 16,32)
        sacc  += __shfl_xor(sacc, 16);
        sacc  += __shfl_xor(sacc, 32);
        ssacc += __shfl_xor(ssacc, 16);
        ssacc += __shfl_xor(ssacc, 32);
        if (q == 0) {
            atomicAdd(&gsum[o], sacc);
            atomicAdd(&gssq[o], ssacc);
        }
    }
}

// ---------------------------------------------------------------------------
// 6) BN + ReLU + untile + transpose (scale/shift computed in-block)
__global__ void k_bnrelu(const unsigned short* __restrict__ y16,
                         const float* __restrict__ gsum, const float* __restrict__ gssq,
                         const float* __restrict__ gamma, const float* __restrict__ beta,
                         float* __restrict__ out) {
    int blk = blockIdx.x;
    int b = blk & 7, h = blk >> 3;
    int pblk = b * 64 + h;
    __shared__ unsigned short T[64 * 257];
    __shared__ float sc[256], sh[256];
    int t = threadIdx.x;
    {
        const float n = 32768.f;
        float mean = gsum[t] / n;
        float var = gssq[t] / n - mean * mean;
        float inv = rsqrtf(var + 1e-5f);
        float s = gamma[t] * inv;
        sc[t] = s;
        sh[t] = beta[t] - mean * s;
    }
    const u16x4* yv = reinterpret_cast<const u16x4*>(y16) + pblk * 4096;
#pragma unroll
    for (int r = 0; r < 16; ++r) {
        int v = t + r * 256;
        u16x4 d = yv[v];
        int lane = v & 63, mt = (v >> 6) & 3, nt = (v >> 8) & 1, wvv = (v >> 9) & 7;
        int p = mt * 16 + (lane >> 4) * 4;
        int o = wvv * 32 + nt * 16 + (lane & 15);
        T[(p + 0) * 257 + o] = d[0];
        T[(p + 1) * 257 + o] = d[1];
        T[(p + 2) * 257 + o] = d[2];
        T[(p + 3) * 257 + o] = d[3];
    }
    __syncthreads();
    int w = t & 63;
    int ob = (t >> 6) * 64;
    float* obase = out + (size_t)b * (256 * 4096) + h * 64 + w;
#pragma unroll 4
    for (int rr = 0; rr < 64; ++rr) {
        int o = ob + rr;
        float v = bf2f(T[w * 257 + o]);
        obase[(size_t)o * 4096] = fmaxf(v * sc[o] + sh[o], 0.f);
    }
}

// ---------------------------------------------------------------------------
extern "C" void kernel_launch(void* const* d_in, const int* in_sizes, int n_in,
                              void* d_out, int out_size, void* d_ws, size_t ws_size,
                              hipStream_t stream) {
    const float* x      = (const float*)d_in[0];
    const float* w_off  = (const float*)d_in[1];
    const float* b_off  = (const float*)d_in[2];
    const float* weight = (const float*)d_in[3];
    const float* bias   = (const float*)d_in[4];
    const float* gamma  = (const float*)d_in[5];
    const float* beta   = (const float*)d_in[6];

    char* ws = (char*)d_ws;
    const size_t OFF_XT    = 0;                       // 16,777,216  bf16 xT
    const size_t OFF_WT    = OFF_XT + 16777216;       //  1,179,648  bf16 wTk
    const size_t OFF_WOFT  = OFF_WT + 1179648;        //    147,456  bf16 wofT
    const size_t OFF_OM    = OFF_WOFT + 147456;       //  4,194,304  f32 om
    const size_t OFF_Y16   = OFF_OM + 4194304;        // 16,777,216  bf16 y tile-layout
    const size_t OFF_SUM   = OFF_Y16 + 16777216;      //      1,024
    const size_t OFF_SUMSQ = OFF_SUM + 1024;

    unsigned short* xT   = (unsigned short*)(ws + OFF_XT);
    unsigned short* wTk  = (unsigned short*)(ws + OFF_WT);
    unsigned short* wofT = (unsigned short*)(ws + OFF_WOFT);
    float* om    = (float*)(ws + OFF_OM);
    unsigned short* y16  = (unsigned short*)(ws + OFF_Y16);
    float* sum   = (float*)(ws + OFF_SUM);
    float* sumsq = (float*)(ws + OFF_SUMSQ);

    hipMemsetAsync(ws + OFF_SUM, 0, 2048, stream);

    k_pack_x   <<<2048, 256, 0, stream>>>(x, xT);
    k_pack_wk  <<<2304, 256, 0, stream>>>(weight, wTk);
    k_pack_woff<<< 288, 256, 0, stream>>>(w_off, wofT);
    k_offconv  <<< 512, 256, 0, stream>>>(xT, wofT, b_off, om);
    k_main     <<< 512, 512, 0, stream>>>(xT, wTk, om, bias, y16, sum, sumsq);
    k_bnrelu   <<< 512, 256, 0, stream>>>(y16, sum, sumsq, gamma, beta, (float*)d_out);
}

// Round 6
// 216.675 us; speedup vs baseline: 1.7147x; 1.0482x over previous
//
#include <hip/hip_runtime.h>
#include <cstdint>

#define BB    8
#define CIN   256
#define COUT  256
#define HH    64
#define WW    64
#define HWSZ  4096
#define NPIX  32768
#define NTAP  9

typedef __attribute__((ext_vector_type(8))) short    s16x8;
typedef __attribute__((ext_vector_type(8))) unsigned short u16x8;
typedef __attribute__((ext_vector_type(4))) unsigned short u16x4;
typedef __attribute__((ext_vector_type(4))) float    f32x4;

__device__ __forceinline__ float bf2f(unsigned short u) {
    unsigned int v = ((unsigned int)u) << 16;
    return __builtin_bit_cast(float, v);
}
__device__ __forceinline__ unsigned short f2bf(float f) {
    unsigned int u = __builtin_bit_cast(unsigned int, f);
    unsigned int r = (u + 0x7FFFu + ((u >> 16) & 1u)) >> 16;   // RNE
    return (unsigned short)r;
}

// ---------------------------------------------------------------------------
// 1) x [B,C,H,W] fp32 -> xT [B,H,W,C] bf16.  b = blk%8 for XCD affinity.
__global__ void k_pack_x(const float* __restrict__ x, unsigned short* __restrict__ xT) {
    int blk = blockIdx.x;
    int b    = blk & 7;
    int rest = blk >> 3;
    int h    = rest >> 2;
    int c0   = (rest & 3) * 64;
    __shared__ float tile[64][65];
    int t = threadIdx.x;
#pragma unroll
    for (int r = 0; r < 16; ++r) {
        int idx = t + r * 256;
        int i = idx >> 6, w = idx & 63;
        tile[i][w] = x[(((b * 256 + c0 + i) * 64 + h) * 64) + w];
    }
    __syncthreads();
#pragma unroll
    for (int r = 0; r < 16; ++r) {
        int idx = t + r * 256;
        int w = idx >> 6, c = idx & 63;
        xT[((b * 64 + h) * 64 + w) * 256 + c0 + c] = f2bf(tile[c][w]);
    }
}

// 2) weight [O,C,3,3] fp32 -> wTk[tap][kc8][n16][o16][q4][j8] bf16 (589,824)
__global__ void k_pack_wk(const float* __restrict__ w, unsigned short* __restrict__ wT) {
    int idx = blockIdx.x * 256 + threadIdx.x;
    int j   = idx & 7;
    int q   = (idx >> 3) & 3;
    int o16 = (idx >> 5) & 15;
    int n16 = (idx >> 9) & 15;
    int kc  = (idx >> 13) & 7;
    int tp  = idx >> 16;
    int c = kc * 32 + q * 8 + j;
    int o = n16 * 16 + o16;
    wT[idx] = f2bf(w[(o * 256 + c) * 9 + tp]);
}

// 3) w_off [27,C,3,3] fp32 -> wofT [tap][j(32,pad0)][c] bf16
__global__ void k_pack_woff(const float* __restrict__ w, unsigned short* __restrict__ wT) {
    int idx = blockIdx.x * 256 + threadIdx.x;
    int c  = idx & 255;
    int j  = (idx >> 8) & 31;
    int tp = idx >> 13;
    float v = (j < 27) ? w[(j * 256 + c) * 9 + tp] : 0.f;
    wT[idx] = f2bf(v);
}

// ---------------------------------------------------------------------------
// 4) offset conv: om[P][32] = conv(x, w_off)+b_off (raw, no sigmoid)
__global__ __launch_bounds__(256, 2)
void k_offconv(const unsigned short* __restrict__ xT,
               const unsigned short* __restrict__ wofT,
               const float* __restrict__ b_off,
               float* __restrict__ om) {
    int blk = blockIdx.x;
    int b = blk & 7, h = blk >> 3;
    int P0 = (b * 64 + h) * 64;
    int t = threadIdx.x;
    int lane = t & 63, wv = t >> 6;
    int p0w = wv * 16;
    int lm = lane & 15, q = lane >> 4;
    __shared__ unsigned short S3[3 * 66 * 136];   // [row][w+pad2][c128+pad8]

    const f32x4 FZ = {0.f, 0.f, 0.f, 0.f};
    f32x4 acc0 = FZ, acc1 = FZ;

    for (int cc = 0; cc < 2; ++cc) {
        __syncthreads();
        if (t < 96) {   // zero the w=0 / w=65 pad columns
            int rr = t >> 5, col = (t >> 4) & 1, c8 = (t & 15) * 8;
            u16x8 z = {0,0,0,0,0,0,0,0};
            *reinterpret_cast<u16x8*>(&S3[(rr * 66 + col * 65) * 136 + c8]) = z;
        }
#pragma unroll
        for (int r = 0; r < 12; ++r) {
            int v = t + r * 256;
            int rr = v >> 10, rem = v & 1023;
            int w = rem >> 4, c8 = (rem & 15) * 8;
            int hr = h + rr - 1;
            u16x8 d = {0,0,0,0,0,0,0,0};
            if (hr >= 0 && hr < 64)
                d = *reinterpret_cast<const u16x8*>(xT + ((b * 64 + hr) * 64 + w) * 256 + cc * 128 + c8);
            *reinterpret_cast<u16x8*>(&S3[(rr * 66 + w + 1) * 136 + c8]) = d;
        }
        __syncthreads();
#pragma unroll
        for (int tp = 0; tp < 9; ++tp) {
            int dh = tp / 3, dw = tp % 3;
            const unsigned short* wb = wofT + (tp * 32 + lm) * 256 + cc * 128;
#pragma unroll
            for (int kc = 0; kc < 4; ++kc) {
                s16x8 a = *reinterpret_cast<const s16x8*>(&S3[(dh * 66 + p0w + lm + dw) * 136 + kc * 32 + q * 8]);
                s16x8 b0 = *reinterpret_cast<const s16x8*>(wb + kc * 32 + q * 8);
                s16x8 b1 = *reinterpret_cast<const s16x8*>(wb + 16 * 256 + kc * 32 + q * 8);
                acc0 = __builtin_amdgcn_mfma_f32_16x16x32_bf16(a, b0, acc0, 0, 0, 0);
                acc1 = __builtin_amdgcn_mfma_f32_16x16x32_bf16(a, b1, acc1, 0, 0, 0);
            }
        }
    }
#pragma unroll
    for (int n = 0; n < 2; ++n) {
        int j = n * 16 + lm;
        float bj = (j < 27) ? b_off[j] : 0.f;
        f32x4 a = n ? acc1 : acc0;
#pragma unroll
        for (int i = 0; i < 4; ++i) {
            int prow = p0w + q * 4 + i;
            om[(P0 + prow) * 32 + j] = a[i] + bj;
        }
    }
}

// ---------------------------------------------------------------------------
// 5) main deform GEMM, producer/consumer wave specialization.
// 512 blocks; 512 thr = 8 waves: wv 0..3 consumers (64px x 64o MFMA),
// wv 4..7 producers (gather+blend tap t+1 while consumers MFMA tap t).
// One barrier per tap; S double-buffered; b = blk%8 XCD affinity.
__global__ __launch_bounds__(512, 4)
void k_main(const unsigned short* __restrict__ xT,
            const unsigned short* __restrict__ wTk,
            const float* __restrict__ om,
            const float* __restrict__ bias,
            unsigned short* __restrict__ y16,
            float* __restrict__ gsum, float* __restrict__ gssq) {
    int blk = blockIdx.x;
    int b = blk & 7, h = blk >> 3;
    int pblk = b * 64 + h;
    int P0 = pblk * 64;
    int t = threadIdx.x;
    int lane = t & 63, wv = t >> 6;
    int lm = lane & 15, q = lane >> 4;

    __shared__ unsigned short S[2][64 * 264];  // sampled tile, double-buffered
    __shared__ float OMS[2048];                // om tile [64px][32]

    {
        float4 tmp = *reinterpret_cast<const float4*>(om + P0 * 32 + t * 4);
        *reinterpret_cast<float4*>(&OMS[t * 4]) = tmp;
    }
    __syncthreads();

    if (wv >= 4) {
        // ------------------------- producer -------------------------
        int pw = wv - 4;
        int p  = pw * 16 + (lane >> 2);    // pixel (w coordinate), 4 lanes each
        int s2 = lane & 3;                 // sub-chunk lane
        int rb = b * 4096;
        float w00, w01, w10, w11;
        int a00, a01, a10, a11;

        auto setup = [&](int tp) {
            float oh = OMS[p * 32 + 2 * tp];
            float ow = OMS[p * 32 + 2 * tp + 1];
            float mv = OMS[p * 32 + 18 + tp];
            float mk = 1.f / (1.f + __expf(-mv));
            float ph = (float)(h + tp / 3 - 1) + oh;
            float pw_ = (float)(p + tp % 3 - 1) + ow;
            float fh0 = floorf(ph), fw0 = floorf(pw_);
            int ih0 = (int)fh0, iw0 = (int)fw0;
            float lh = ph - fh0, lw = pw_ - fw0;
            float hh = 1.f - lh, hw_ = 1.f - lw;
            bool vh0 = (ih0 >= 0) & (ih0 < 64);
            bool vh1 = (ih0 + 1 >= 0) & (ih0 + 1 < 64);
            bool vw0 = (iw0 >= 0) & (iw0 < 64);
            bool vw1 = (iw0 + 1 >= 0) & (iw0 + 1 < 64);
            w00 = hh * hw_ * mk * (float)(vh0 & vw0);
            w01 = hh * lw  * mk * (float)(vh0 & vw1);
            w10 = lh * hw_ * mk * (float)(vh1 & vw0);
            w11 = lh * lw  * mk * (float)(vh1 & vw1);
            int ch0 = min(max(ih0, 0), 63), ch1 = min(max(ih0 + 1, 0), 63);
            int cw0 = min(max(iw0, 0), 63), cw1 = min(max(iw0 + 1, 0), 63);
            a00 = ((rb + ch0 * 64 + cw0) * 256) + s2 * 8;
            a01 = ((rb + ch0 * 64 + cw1) * 256) + s2 * 8;
            a10 = ((rb + ch1 * 64 + cw0) * 256) + s2 * 8;
            a11 = ((rb + ch1 * 64 + cw1) * 256) + s2 * 8;
        };

        u16x8 rA[8], rB[8];
        auto issueQ = [&](int qq, u16x8* r) {
            int co = qq * 64;
#pragma unroll
            for (int j = 0; j < 2; ++j) {
                r[0 + j] = *reinterpret_cast<const u16x8*>(xT + a00 + co + j * 32);
                r[2 + j] = *reinterpret_cast<const u16x8*>(xT + a01 + co + j * 32);
                r[4 + j] = *reinterpret_cast<const u16x8*>(xT + a10 + co + j * 32);
                r[6 + j] = *reinterpret_cast<const u16x8*>(xT + a11 + co + j * 32);
            }
        };
        auto blendQ = [&](int buf, int qq, u16x8* r) {
#pragma unroll
            for (int j = 0; j < 2; ++j) {
                u16x8 res;
#pragma unroll
                for (int k = 0; k < 8; ++k) {
                    float v = w00 * bf2f(r[0 + j][k]);
                    v = fmaf(w01, bf2f(r[2 + j][k]), v);
                    v = fmaf(w10, bf2f(r[4 + j][k]), v);
                    v = fmaf(w11, bf2f(r[6 + j][k]), v);
                    res[k] = f2bf(v);
                }
                *reinterpret_cast<u16x8*>(&S[buf][p * 264 + qq * 64 + j * 32 + s2 * 8]) = res;
            }
        };
        auto fillTap = [&](int tp, int buf) {
            setup(tp);
            issueQ(0, rA);
            issueQ(1, rB);
            blendQ(buf, 0, rA);
            issueQ(2, rA);
            blendQ(buf, 1, rB);
            issueQ(3, rB);
            blendQ(buf, 2, rA);
            blendQ(buf, 3, rB);
        };

        fillTap(0, 0);                 // prologue: tap 0 -> S[0]
        __syncthreads();
        for (int tp = 0; tp < 9; ++tp) {
            if (tp < 8) fillTap(tp + 1, (tp + 1) & 1);
            __syncthreads();
        }
        // producers exit (no epilogue)
    } else {
        // ------------------------- consumer -------------------------
        int o0 = wv * 64;
        const f32x4 FZ = {0.f, 0.f, 0.f, 0.f};
        f32x4 acc[4][4];
#pragma unroll
        for (int m = 0; m < 4; ++m)
#pragma unroll
            for (int n = 0; n < 4; ++n) acc[m][n] = FZ;

        __syncthreads();               // matches producer prologue barrier
        for (int tp = 0; tp < 9; ++tp) {
            const unsigned short* Sc = &S[tp & 1][0];
            const unsigned short* wtap = wTk + (size_t)tp * 65536
                                       + (size_t)(wv * 4) * 512 + lm * 32 + q * 8;
#pragma unroll
            for (int kc = 0; kc < 8; ++kc) {
                const unsigned short* wb = wtap + kc * 8192;
                s16x8 bf0 = *reinterpret_cast<const s16x8*>(wb);
                s16x8 bf1 = *reinterpret_cast<const s16x8*>(wb + 512);
                s16x8 bf2 = *reinterpret_cast<const s16x8*>(wb + 1024);
                s16x8 bf3 = *reinterpret_cast<const s16x8*>(wb + 1536);
#pragma unroll
                for (int mt = 0; mt < 4; ++mt) {
                    s16x8 a = *reinterpret_cast<const s16x8*>(
                        &Sc[(mt * 16 + lm) * 264 + kc * 32 + q * 8]);
                    acc[mt][0] = __builtin_amdgcn_mfma_f32_16x16x32_bf16(a, bf0, acc[mt][0], 0, 0, 0);
                    acc[mt][1] = __builtin_amdgcn_mfma_f32_16x16x32_bf16(a, bf1, acc[mt][1], 0, 0, 0);
                    acc[mt][2] = __builtin_amdgcn_mfma_f32_16x16x32_bf16(a, bf2, acc[mt][2], 0, 0, 0);
                    acc[mt][3] = __builtin_amdgcn_mfma_f32_16x16x32_bf16(a, bf3, acc[mt][3], 0, 0, 0);
                }
            }
            __syncthreads();
        }

        // epilogue: y16 (bf16, tile layout) + stats (shuffle reduce + atomics)
        u16x4* yv = reinterpret_cast<u16x4*>(y16);
#pragma unroll
        for (int nt = 0; nt < 4; ++nt) {
            int o = o0 + nt * 16 + lm;
            float bo = bias[o];
            float sacc = 0.f, ssacc = 0.f;
#pragma unroll
            for (int mt = 0; mt < 4; ++mt) {
                u16x4 st;
#pragma unroll
                for (int i = 0; i < 4; ++i) {
                    float v = acc[mt][nt][i] + bo;
                    st[i] = f2bf(v);
                    sacc += v; ssacc += v * v;
                }
                int idx4 = ((pblk * 4 + wv) * 16 + nt * 4 + mt) * 64 + lane;
                yv[idx4] = st;
            }
            sacc  += __shfl_xor(sacc, 16);
            sacc  += __shfl_xor(sacc, 32);
            ssacc += __shfl_xor(ssacc, 16);
            ssacc += __shfl_xor(ssacc, 32);
            if (q == 0) {
                atomicAdd(&gsum[o], sacc);
                atomicAdd(&gssq[o], ssacc);
            }
        }
    }
}

// ---------------------------------------------------------------------------
// 6) BN + ReLU + untile + transpose (scale/shift computed in-block)
__global__ void k_bnrelu(const unsigned short* __restrict__ y16,
                         const float* __restrict__ gsum, const float* __restrict__ gssq,
                         const float* __restrict__ gamma, const float* __restrict__ beta,
                         float* __restrict__ out) {
    int blk = blockIdx.x;
    int b = blk & 7, h = blk >> 3;
    int pblk = b * 64 + h;
    __shared__ unsigned short T[64 * 257];
    __shared__ float sc[256], sh[256];
    int t = threadIdx.x;
    {
        const float n = 32768.f;
        float mean = gsum[t] / n;
        float var = gssq[t] / n - mean * mean;
        float inv = rsqrtf(var + 1e-5f);
        float s = gamma[t] * inv;
        sc[t] = s;
        sh[t] = beta[t] - mean * s;
    }
    const u16x4* yv = reinterpret_cast<const u16x4*>(y16) + pblk * 4096;
#pragma unroll
    for (int r = 0; r < 16; ++r) {
        int v = t + r * 256;
        u16x4 d = yv[v];
        int lane = v & 63, mt = (v >> 6) & 3, nt = (v >> 8) & 3, wvv = (v >> 10) & 3;
        int p = mt * 16 + (lane >> 4) * 4;
        int o = wvv * 64 + nt * 16 + (lane & 15);
        T[(p + 0) * 257 + o] = d[0];
        T[(p + 1) * 257 + o] = d[1];
        T[(p + 2) * 257 + o] = d[2];
        T[(p + 3) * 257 + o] = d[3];
    }
    __syncthreads();
    int w = t & 63;
    int ob = (t >> 6) * 64;
    float* obase = out + (size_t)b * (256 * 4096) + h * 64 + w;
#pragma unroll 4
    for (int rr = 0; rr < 64; ++rr) {
        int o = ob + rr;
        float v = bf2f(T[w * 257 + o]);
        obase[(size_t)o * 4096] = fmaxf(v * sc[o] + sh[o], 0.f);
    }
}

// ---------------------------------------------------------------------------
extern "C" void kernel_launch(void* const* d_in, const int* in_sizes, int n_in,
                              void* d_out, int out_size, void* d_ws, size_t ws_size,
                              hipStream_t stream) {
    const float* x      = (const float*)d_in[0];
    const float* w_off  = (const float*)d_in[1];
    const float* b_off  = (const float*)d_in[2];
    const float* weight = (const float*)d_in[3];
    const float* bias   = (const float*)d_in[4];
    const float* gamma  = (const float*)d_in[5];
    const float* beta   = (const float*)d_in[6];

    char* ws = (char*)d_ws;
    const size_t OFF_XT    = 0;                       // 16,777,216  bf16 xT
    const size_t OFF_WT    = OFF_XT + 16777216;       //  1,179,648  bf16 wTk
    const size_t OFF_WOFT  = OFF_WT + 1179648;        //    147,456  bf16 wofT
    const size_t OFF_OM    = OFF_WOFT + 147456;       //  4,194,304  f32 om
    const size_t OFF_Y16   = OFF_OM + 4194304;        // 16,777,216  bf16 y tile-layout
    const size_t OFF_SUM   = OFF_Y16 + 16777216;      //      1,024
    const size_t OFF_SUMSQ = OFF_SUM + 1024;

    unsigned short* xT   = (unsigned short*)(ws + OFF_XT);
    unsigned short* wTk  = (unsigned short*)(ws + OFF_WT);
    unsigned short* wofT = (unsigned short*)(ws + OFF_WOFT);
    float* om    = (float*)(ws + OFF_OM);
    unsigned short* y16  = (unsigned short*)(ws + OFF_Y16);
    float* sum   = (float*)(ws + OFF_SUM);
    float* sumsq = (float*)(ws + OFF_SUMSQ);

    hipMemsetAsync(ws + OFF_SUM, 0, 2048, stream);

    k_pack_x   <<<2048, 256, 0, stream>>>(x, xT);
    k_pack_wk  <<<2304, 256, 0, stream>>>(weight, wTk);
    k_pack_woff<<< 288, 256, 0, stream>>>(w_off, wofT);
    k_offconv  <<< 512, 256, 0, stream>>>(xT, wofT, b_off, om);
    k_main     <<< 512, 512, 0, stream>>>(xT, wTk, om, bias, y16, sum, sumsq);
    k_bnrelu   <<< 512, 256, 0, stream>>>(y16, sum, sumsq, gamma, beta, (float*)d_out);
}

// Round 7
// 211.406 us; speedup vs baseline: 1.7574x; 1.0249x over previous
//
#include <hip/hip_runtime.h>
#include <cstdint>

#define BB    8
#define CIN   256
#define COUT  256
#define HH    64
#define WW    64
#define HWSZ  4096
#define NPIX  32768
#define NTAP  9

typedef __attribute__((ext_vector_type(8))) short    s16x8;
typedef __attribute__((ext_vector_type(8))) unsigned short u16x8;
typedef __attribute__((ext_vector_type(4))) unsigned short u16x4;
typedef __attribute__((ext_vector_type(4))) float    f32x4;

__device__ __forceinline__ float bf2f(unsigned short u) {
    unsigned int v = ((unsigned int)u) << 16;
    return __builtin_bit_cast(float, v);
}
__device__ __forceinline__ unsigned short f2bf(float f) {
    unsigned int u = __builtin_bit_cast(unsigned int, f);
    unsigned int r = (u + 0x7FFFu + ((u >> 16) & 1u)) >> 16;   // RNE
    return (unsigned short)r;
}

// ---------------------------------------------------------------------------
// 1) x [B,C,H,W] fp32 -> xT [B,H,W,C] bf16.  b = blk%8 XCD affinity.
// Stores vectorized: u16x8 (16B/lane).
__global__ void k_pack_x(const float* __restrict__ x, unsigned short* __restrict__ xT) {
    int blk = blockIdx.x;
    int b    = blk & 7;
    int rest = blk >> 3;
    int h    = rest >> 2;
    int c0   = (rest & 3) * 64;
    __shared__ float tile[64][65];
    int t = threadIdx.x;
#pragma unroll
    for (int r = 0; r < 16; ++r) {
        int idx = t + r * 256;
        int i = idx >> 6, w = idx & 63;
        tile[i][w] = x[(((b * 256 + c0 + i) * 64 + h) * 64) + w];
    }
    __syncthreads();
#pragma unroll
    for (int r = 0; r < 2; ++r) {
        int idx = t + r * 256;          // 0..511 = (w, c8)
        int w  = idx >> 3;
        int c8 = (idx & 7) * 8;
        u16x8 res;
#pragma unroll
        for (int k = 0; k < 8; ++k) res[k] = f2bf(tile[c8 + k][w]);
        *reinterpret_cast<u16x8*>(&xT[((b * 64 + h) * 64 + w) * 256 + c0 + c8]) = res;
    }
}

// 2+3) weight packs merged into one launch.
// wTk[tap][kc8][n16][o16][q4][j8] bf16 (589,824); wofT [tap][j32][c] (73,728)
__global__ void k_pack_w2(const float* __restrict__ w, const float* __restrict__ woff,
                          unsigned short* __restrict__ wT, unsigned short* __restrict__ wofT) {
    int bid = blockIdx.x;
    int t = threadIdx.x;
    if (bid < 2304) {
        int idx = bid * 256 + t;
        int j   = idx & 7;
        int q   = (idx >> 3) & 3;
        int o16 = (idx >> 5) & 15;
        int n16 = (idx >> 9) & 15;
        int kc  = (idx >> 13) & 7;
        int tp  = idx >> 16;
        int c = kc * 32 + q * 8 + j;
        int o = n16 * 16 + o16;
        wT[idx] = f2bf(w[(o * 256 + c) * 9 + tp]);
    } else {
        int idx = (bid - 2304) * 256 + t;
        int c  = idx & 255;
        int j  = (idx >> 8) & 31;
        int tp = idx >> 13;
        float v = (j < 27) ? woff[(j * 256 + c) * 9 + tp] : 0.f;
        wofT[idx] = f2bf(v);
    }
}

// ---------------------------------------------------------------------------
// 4) offset conv: om[P][32] = conv(x, w_off)+b_off (raw, no sigmoid)
__global__ __launch_bounds__(256, 2)
void k_offconv(const unsigned short* __restrict__ xT,
               const unsigned short* __restrict__ wofT,
               const float* __restrict__ b_off,
               float* __restrict__ om) {
    int blk = blockIdx.x;
    int b = blk & 7, h = blk >> 3;
    int P0 = (b * 64 + h) * 64;
    int t = threadIdx.x;
    int lane = t & 63, wv = t >> 6;
    int p0w = wv * 16;
    int lm = lane & 15, q = lane >> 4;
    __shared__ unsigned short S3[3 * 66 * 136];   // [row][w+pad2][c128+pad8]

    const f32x4 FZ = {0.f, 0.f, 0.f, 0.f};
    f32x4 acc0 = FZ, acc1 = FZ;

    for (int cc = 0; cc < 2; ++cc) {
        __syncthreads();
        if (t < 96) {   // zero the w=0 / w=65 pad columns
            int rr = t >> 5, col = (t >> 4) & 1, c8 = (t & 15) * 8;
            u16x8 z = {0,0,0,0,0,0,0,0};
            *reinterpret_cast<u16x8*>(&S3[(rr * 66 + col * 65) * 136 + c8]) = z;
        }
#pragma unroll
        for (int r = 0; r < 12; ++r) {
            int v = t + r * 256;
            int rr = v >> 10, rem = v & 1023;
            int w = rem >> 4, c8 = (rem & 15) * 8;
            int hr = h + rr - 1;
            u16x8 d = {0,0,0,0,0,0,0,0};
            if (hr >= 0 && hr < 64)
                d = *reinterpret_cast<const u16x8*>(xT + ((b * 64 + hr) * 64 + w) * 256 + cc * 128 + c8);
            *reinterpret_cast<u16x8*>(&S3[(rr * 66 + w + 1) * 136 + c8]) = d;
        }
        __syncthreads();
#pragma unroll
        for (int tp = 0; tp < 9; ++tp) {
            int dh = tp / 3, dw = tp % 3;
            const unsigned short* wb = wofT + (tp * 32 + lm) * 256 + cc * 128;
#pragma unroll
            for (int kc = 0; kc < 4; ++kc) {
                s16x8 a = *reinterpret_cast<const s16x8*>(&S3[(dh * 66 + p0w + lm + dw) * 136 + kc * 32 + q * 8]);
                s16x8 b0 = *reinterpret_cast<const s16x8*>(wb + kc * 32 + q * 8);
                s16x8 b1 = *reinterpret_cast<const s16x8*>(wb + 16 * 256 + kc * 32 + q * 8);
                acc0 = __builtin_amdgcn_mfma_f32_16x16x32_bf16(a, b0, acc0, 0, 0, 0);
                acc1 = __builtin_amdgcn_mfma_f32_16x16x32_bf16(a, b1, acc1, 0, 0, 0);
            }
        }
    }
#pragma unroll
    for (int n = 0; n < 2; ++n) {
        int j = n * 16 + lm;
        float bj = (j < 27) ? b_off[j] : 0.f;
        f32x4 a = n ? acc1 : acc0;
#pragma unroll
        for (int i = 0; i < 4; ++i) {
            int prow = p0w + q * 4 + i;
            om[(P0 + prow) * 32 + j] = a[i] + bj;
        }
    }
}

// ---------------------------------------------------------------------------
// 5) main deform GEMM, producer/consumer wave specialization.
// Producers: 8 lanes/px (full 128B-aligned runs per gather inst), 2 px-groups.
// Consumers: 64px x 64o, weight kc+1 register prefetch.
__global__ __launch_bounds__(512, 4)
void k_main(const unsigned short* __restrict__ xT,
            const unsigned short* __restrict__ wTk,
            const float* __restrict__ om,
            const float* __restrict__ bias,
            unsigned short* __restrict__ y16,
            float* __restrict__ gsum, float* __restrict__ gssq) {
    int blk = blockIdx.x;
    int b = blk & 7, h = blk >> 3;
    int pblk = b * 64 + h;
    int P0 = pblk * 64;
    int t = threadIdx.x;
    int lane = t & 63, wv = t >> 6;
    int lm = lane & 15, q = lane >> 4;

    __shared__ unsigned short S[2][64 * 264];  // sampled tile, double-buffered
    __shared__ float OMS[64 * 33];             // om tile, padded stride 33

    {
        int v = t * 4;
        int p = v >> 5, j = v & 31;
        float4 tmp = *reinterpret_cast<const float4*>(om + P0 * 32 + v);
        OMS[p * 33 + j]     = tmp.x;
        OMS[p * 33 + j + 1] = tmp.y;
        OMS[p * 33 + j + 2] = tmp.z;
        OMS[p * 33 + j + 3] = tmp.w;
    }
    __syncthreads();

    if (wv >= 4) {
        // ------------------------- producer -------------------------
        int pw = wv - 4;
        int s  = lane & 7;                 // 16B sub-chunk within 128B window
        int pA = pw * 16 + (lane >> 3);    // group A pixel (8 lanes each)
        int pB = pA + 8;                   // group B pixel
        int rb = b * 4096;

        float wgA[4], wgB[4];
        int   adA[4], adB[4];

        auto setup = [&](int tp, int p, float* wg, int* ad) {
            float oh = OMS[p * 33 + 2 * tp];
            float ow = OMS[p * 33 + 2 * tp + 1];
            float mv = OMS[p * 33 + 18 + tp];
            float mk = 1.f / (1.f + __expf(-mv));
            float ph = (float)(h + tp / 3 - 1) + oh;
            float pw_ = (float)(p + tp % 3 - 1) + ow;
            float fh0 = floorf(ph), fw0 = floorf(pw_);
            int ih0 = (int)fh0, iw0 = (int)fw0;
            float lh = ph - fh0, lw = pw_ - fw0;
            float hh = 1.f - lh, hw_ = 1.f - lw;
            bool vh0 = (ih0 >= 0) & (ih0 < 64);
            bool vh1 = (ih0 + 1 >= 0) & (ih0 + 1 < 64);
            bool vw0 = (iw0 >= 0) & (iw0 < 64);
            bool vw1 = (iw0 + 1 >= 0) & (iw0 + 1 < 64);
            wg[0] = hh * hw_ * mk * (float)(vh0 & vw0);
            wg[1] = hh * lw  * mk * (float)(vh0 & vw1);
            wg[2] = lh * hw_ * mk * (float)(vh1 & vw0);
            wg[3] = lh * lw  * mk * (float)(vh1 & vw1);
            int ch0 = min(max(ih0, 0), 63), ch1 = min(max(ih0 + 1, 0), 63);
            int cw0 = min(max(iw0, 0), 63), cw1 = min(max(iw0 + 1, 0), 63);
            ad[0] = ((rb + ch0 * 64 + cw0) * 256);
            ad[1] = ((rb + ch0 * 64 + cw1) * 256);
            ad[2] = ((rb + ch1 * 64 + cw0) * 256);
            ad[3] = ((rb + ch1 * 64 + cw1) * 256);
        };

        u16x8 rP[4], rQ[4];
        auto issueSet = [&](const int* ad, int j, u16x8* r) {
            int off = j * 64 + s * 8;
#pragma unroll
            for (int c = 0; c < 4; ++c)
                r[c] = *reinterpret_cast<const u16x8*>(xT + ad[c] + off);
        };
        auto blendSet = [&](int buf, int p, const float* wg, int j, u16x8* r) {
            u16x8 res;
#pragma unroll
            for (int k = 0; k < 8; ++k) {
                float v = wg[0] * bf2f(r[0][k]);
                v = fmaf(wg[1], bf2f(r[1][k]), v);
                v = fmaf(wg[2], bf2f(r[2][k]), v);
                v = fmaf(wg[3], bf2f(r[3][k]), v);
                res[k] = f2bf(v);
            }
            *reinterpret_cast<u16x8*>(&S[buf][p * 264 + j * 64 + s * 8]) = res;
        };
        auto fillTap = [&](int tp, int buf) {
            setup(tp, pA, wgA, adA);
            setup(tp, pB, wgB, adB);
            issueSet(adA, 0, rP);
            issueSet(adA, 1, rQ);
            blendSet(buf, pA, wgA, 0, rP);  issueSet(adA, 2, rP);
            blendSet(buf, pA, wgA, 1, rQ);  issueSet(adA, 3, rQ);
            blendSet(buf, pA, wgA, 2, rP);  issueSet(adB, 0, rP);
            blendSet(buf, pA, wgA, 3, rQ);  issueSet(adB, 1, rQ);
            blendSet(buf, pB, wgB, 0, rP);  issueSet(adB, 2, rP);
            blendSet(buf, pB, wgB, 1, rQ);  issueSet(adB, 3, rQ);
            blendSet(buf, pB, wgB, 2, rP);
            blendSet(buf, pB, wgB, 3, rQ);
        };

        fillTap(0, 0);
        __syncthreads();
        for (int tp = 0; tp < 9; ++tp) {
            if (tp < 8) fillTap(tp + 1, (tp + 1) & 1);
            __syncthreads();
        }
    } else {
        // ------------------------- consumer -------------------------
        int o0 = wv * 64;
        const f32x4 FZ = {0.f, 0.f, 0.f, 0.f};
        f32x4 acc[4][4];
#pragma unroll
        for (int m = 0; m < 4; ++m)
#pragma unroll
            for (int n = 0; n < 4; ++n) acc[m][n] = FZ;

        __syncthreads();               // matches producer prologue barrier
        for (int tp = 0; tp < 9; ++tp) {
            const unsigned short* Sc = &S[tp & 1][0];
            const unsigned short* wtap = wTk + (size_t)tp * 65536
                                       + (size_t)(wv * 4) * 512 + lm * 32 + q * 8;
            s16x8 wbuf[2][4];
#pragma unroll
            for (int n = 0; n < 4; ++n)
                wbuf[0][n] = *reinterpret_cast<const s16x8*>(wtap + n * 512);
#pragma unroll
            for (int kc = 0; kc < 8; ++kc) {
                if (kc < 7) {
                    const unsigned short* wb = wtap + (kc + 1) * 8192;
#pragma unroll
                    for (int n = 0; n < 4; ++n)
                        wbuf[(kc + 1) & 1][n] = *reinterpret_cast<const s16x8*>(wb + n * 512);
                }
#pragma unroll
                for (int mt = 0; mt < 4; ++mt) {
                    s16x8 a = *reinterpret_cast<const s16x8*>(
                        &Sc[(mt * 16 + lm) * 264 + kc * 32 + q * 8]);
#pragma unroll
                    for (int n = 0; n < 4; ++n)
                        acc[mt][n] = __builtin_amdgcn_mfma_f32_16x16x32_bf16(
                            a, wbuf[kc & 1][n], acc[mt][n], 0, 0, 0);
                }
            }
            __syncthreads();
        }

        // epilogue: y16 (bf16, tile layout) + stats (shuffle reduce + atomics)
        u16x4* yv = reinterpret_cast<u16x4*>(y16);
#pragma unroll
        for (int nt = 0; nt < 4; ++nt) {
            int o = o0 + nt * 16 + lm;
            float bo = bias[o];
            float sacc = 0.f, ssacc = 0.f;
#pragma unroll
            for (int mt = 0; mt < 4; ++mt) {
                u16x4 st;
#pragma unroll
                for (int i = 0; i < 4; ++i) {
                    float v = acc[mt][nt][i] + bo;
                    st[i] = f2bf(v);
                    sacc += v; ssacc += v * v;
                }
                int idx4 = ((pblk * 4 + wv) * 16 + nt * 4 + mt) * 64 + lane;
                yv[idx4] = st;
            }
            sacc  += __shfl_xor(sacc, 16);
            sacc  += __shfl_xor(sacc, 32);
            ssacc += __shfl_xor(ssacc, 16);
            ssacc += __shfl_xor(ssacc, 32);
            if (q == 0) {
                atomicAdd(&gsum[o], sacc);
                atomicAdd(&gssq[o], ssacc);
            }
        }
    }
}

// ---------------------------------------------------------------------------
// 6) BN + ReLU + untile + transpose; float4 stores (16B/lane)
__global__ void k_bnrelu(const unsigned short* __restrict__ y16,
                         const float* __restrict__ gsum, const float* __restrict__ gssq,
                         const float* __restrict__ gamma, const float* __restrict__ beta,
                         float* __restrict__ out) {
    int blk = blockIdx.x;
    int b = blk & 7, h = blk >> 3;
    int pblk = b * 64 + h;
    __shared__ unsigned short T[64 * 257];
    __shared__ float sc[256], sh[256];
    int t = threadIdx.x;
    {
        const float n = 32768.f;
        float mean = gsum[t] / n;
        float var = gssq[t] / n - mean * mean;
        float inv = rsqrtf(var + 1e-5f);
        float s = gamma[t] * inv;
        sc[t] = s;
        sh[t] = beta[t] - mean * s;
    }
    const u16x4* yv = reinterpret_cast<const u16x4*>(y16) + pblk * 4096;
#pragma unroll
    for (int r = 0; r < 16; ++r) {
        int v = t + r * 256;
        u16x4 d = yv[v];
        int lane = v & 63, mt = (v >> 6) & 3, nt = (v >> 8) & 3, wvv = (v >> 10) & 3;
        int p = mt * 16 + (lane >> 4) * 4;
        int o = wvv * 64 + nt * 16 + (lane & 15);
        T[(p + 0) * 257 + o] = d[0];
        T[(p + 1) * 257 + o] = d[1];
        T[(p + 2) * 257 + o] = d[2];
        T[(p + 3) * 257 + o] = d[3];
    }
    __syncthreads();
    int w4   = (t & 15) * 4;
    int orow = t >> 4;
    float* obase = out + (size_t)b * (256 * 4096) + h * 64;
#pragma unroll
    for (int it = 0; it < 16; ++it) {
        int o = orow + it * 16;
        float scl = sc[o], shf = sh[o];
        float4 vo;
        vo.x = fmaxf(bf2f(T[(w4 + 0) * 257 + o]) * scl + shf, 0.f);
        vo.y = fmaxf(bf2f(T[(w4 + 1) * 257 + o]) * scl + shf, 0.f);
        vo.z = fmaxf(bf2f(T[(w4 + 2) * 257 + o]) * scl + shf, 0.f);
        vo.w = fmaxf(bf2f(T[(w4 + 3) * 257 + o]) * scl + shf, 0.f);
        *reinterpret_cast<float4*>(obase + (size_t)o * 4096 + w4) = vo;
    }
}

// ---------------------------------------------------------------------------
extern "C" void kernel_launch(void* const* d_in, const int* in_sizes, int n_in,
                              void* d_out, int out_size, void* d_ws, size_t ws_size,
                              hipStream_t stream) {
    const float* x      = (const float*)d_in[0];
    const float* w_off  = (const float*)d_in[1];
    const float* b_off  = (const float*)d_in[2];
    const float* weight = (const float*)d_in[3];
    const float* bias   = (const float*)d_in[4];
    const float* gamma  = (const float*)d_in[5];
    const float* beta   = (const float*)d_in[6];

    char* ws = (char*)d_ws;
    const size_t OFF_XT    = 0;                       // 16,777,216  bf16 xT
    const size_t OFF_WT    = OFF_XT + 16777216;       //  1,179,648  bf16 wTk
    const size_t OFF_WOFT  = OFF_WT + 1179648;        //    147,456  bf16 wofT
    const size_t OFF_OM    = OFF_WOFT + 147456;       //  4,194,304  f32 om
    const size_t OFF_Y16   = OFF_OM + 4194304;        // 16,777,216  bf16 y tile-layout
    const size_t OFF_SUM   = OFF_Y16 + 16777216;      //      1,024
    const size_t OFF_SUMSQ = OFF_SUM + 1024;

    unsigned short* xT   = (unsigned short*)(ws + OFF_XT);
    unsigned short* wTk  = (unsigned short*)(ws + OFF_WT);
    unsigned short* wofT = (unsigned short*)(ws + OFF_WOFT);
    float* om    = (float*)(ws + OFF_OM);
    unsigned short* y16  = (unsigned short*)(ws + OFF_Y16);
    float* sum   = (float*)(ws + OFF_SUM);
    float* sumsq = (float*)(ws + OFF_SUMSQ);

    hipMemsetAsync(ws + OFF_SUM, 0, 2048, stream);

    k_pack_x <<<2048, 256, 0, stream>>>(x, xT);
    k_pack_w2<<<2592, 256, 0, stream>>>(weight, w_off, wTk, wofT);
    k_offconv<<< 512, 256, 0, stream>>>(xT, wofT, b_off, om);
    k_main   <<< 512, 512, 0, stream>>>(xT, wTk, om, bias, y16, sum, sumsq);
    k_bnrelu <<< 512, 256, 0, stream>>>(y16, sum, sumsq, gamma, beta, (float*)d_out);
}

// Round 9
// 207.163 us; speedup vs baseline: 1.7934x; 1.0205x over previous
//
#include <hip/hip_runtime.h>
#include <cstdint>

#define BB    8
#define CIN   256
#define COUT  256
#define HH    64
#define WW    64

typedef __attribute__((ext_vector_type(8))) short    s16x8;
typedef __attribute__((ext_vector_type(8))) unsigned short u16x8;
typedef __attribute__((ext_vector_type(4))) unsigned short u16x4;
typedef __attribute__((ext_vector_type(4))) float    f32x4;

__device__ __forceinline__ float bf2f(unsigned short u) {
    unsigned int v = ((unsigned int)u) << 16;
    return __builtin_bit_cast(float, v);
}
__device__ __forceinline__ unsigned short f2bf(float f) {
    unsigned int u = __builtin_bit_cast(unsigned int, f);
    unsigned int r = (u + 0x7FFFu + ((u >> 16) & 1u)) >> 16;   // RNE
    return (unsigned short)r;
}

// ---------------------------------------------------------------------------
// 1) merged packs, 4640 blocks x 256 thr:
//    blk 0..2047   : x [B,C,H,W] fp32 -> xT [B,H,W,C] bf16 (b=blk&7 XCD affinity)
//    blk 2048..4351: weight -> wTk[tap][kc8][n16][o16][q4][j8] bf16
//    blk 4352..4639: w_off  -> wofT[tap][j32][c] bf16
__global__ void k_pack(const float* __restrict__ x,
                       const float* __restrict__ w,
                       const float* __restrict__ woff,
                       unsigned short* __restrict__ xT,
                       unsigned short* __restrict__ wTk,
                       unsigned short* __restrict__ wofT) {
    int blk = blockIdx.x;
    int t = threadIdx.x;
    __shared__ float tile[64 * 65];
    if (blk < 2048) {
        int b    = blk & 7;
        int rest = blk >> 3;
        int h    = rest >> 2;
        int c0   = (rest & 3) * 64;
#pragma unroll
        for (int r = 0; r < 16; ++r) {
            int idx = t + r * 256;
            int i = idx >> 6, w_ = idx & 63;
            tile[i * 65 + w_] = x[(((b * 256 + c0 + i) * 64 + h) * 64) + w_];
        }
        __syncthreads();
#pragma unroll
        for (int r = 0; r < 2; ++r) {
            int idx = t + r * 256;          // 0..511 = (w, c8)
            int w_ = idx >> 3;
            int c8 = (idx & 7) * 8;
            u16x8 res;
#pragma unroll
            for (int k = 0; k < 8; ++k) res[k] = f2bf(tile[(c8 + k) * 65 + w_]);
            *reinterpret_cast<u16x8*>(&xT[((b * 64 + h) * 64 + w_) * 256 + c0 + c8]) = res;
        }
    } else if (blk < 4352) {
        int idx = (blk - 2048) * 256 + t;   // 0..589,823
        int j   = idx & 7;
        int q   = (idx >> 3) & 3;
        int o16 = (idx >> 5) & 15;
        int n16 = (idx >> 9) & 15;
        int kc  = (idx >> 13) & 7;
        int tp  = idx >> 16;
        int c = kc * 32 + q * 8 + j;
        int o = n16 * 16 + o16;
        wTk[idx] = f2bf(w[(o * 256 + c) * 9 + tp]);
    } else {
        int idx = (blk - 4352) * 256 + t;   // 0..73,727
        int c  = idx & 255;
        int j  = (idx >> 8) & 31;
        int tp = idx >> 13;
        wofT[idx] = f2bf((j < 27) ? woff[(j * 256 + c) * 9 + tp] : 0.f);
    }
}

// ---------------------------------------------------------------------------
// 2) main kernel: offconv (B1, om in LDS) + deform GEMM (B2, producer/consumer)
//    + epilogue (y16 tile-layout + stats atomics).
// 512 blocks (one per (b,h), b=blk&7 XCD affinity), 512 thr = 8 waves.
// LDS union (76032 B):
//   [0,53856)     S3 offconv 3-row window (3*66*136 u16)   | B1
//   [0,67584)     S sampled-tap double buffer (2x64x264)    | B2
//   [67584,76032) OMS om tile (64px x 33 f32)               | B1 write, B2 read
__global__ __launch_bounds__(512, 4)
void k_main(const unsigned short* __restrict__ xT,
            const unsigned short* __restrict__ wTk,
            const unsigned short* __restrict__ wofT,
            const float* __restrict__ boffg,
            const float* __restrict__ bias,
            unsigned short* __restrict__ y16,
            float* __restrict__ gsum, float* __restrict__ gssq) {
    __shared__ __align__(16) char smem[76032];
    int blk = blockIdx.x;
    int b = blk & 7, h = blk >> 3;
    int pblk = b * 64 + h;
    int t = threadIdx.x;
    int lane = t & 63, wv = t >> 6;
    int lm = lane & 15, q = lane >> 4;
    const f32x4 FZ = {0.f, 0.f, 0.f, 0.f};

    // ===================== Phase B1: offset conv -> OMS =====================
    {
        unsigned short* S3 = (unsigned short*)smem;          // [3*66*136]
        float* OMS = (float*)(smem + 67584);                 // [64*33]
        f32x4 oacc0 = FZ, oacc1 = FZ;
        int p0w = wv * 16;   // only wv<4 meaningful
        for (int cc = 0; cc < 2; ++cc) {
            __syncthreads();
            if (t < 96) {    // zero w=0 / w=65 pad columns
                int rr = t >> 5, col = (t >> 4) & 1, c8 = (t & 15) * 8;
                u16x8 z = {0,0,0,0,0,0,0,0};
                *reinterpret_cast<u16x8*>(&S3[(rr * 66 + col * 65) * 136 + c8]) = z;
            }
#pragma unroll
            for (int r = 0; r < 6; ++r) {
                int v = t + r * 512;               // over 3*64*16 vec8 units
                int rr = v >> 10, rem = v & 1023;
                int w_ = rem >> 4, c8 = (rem & 15) * 8;
                int hr = h + rr - 1;
                u16x8 d = {0,0,0,0,0,0,0,0};
                if (hr >= 0 && hr < 64)
                    d = *reinterpret_cast<const u16x8*>(xT + ((b * 64 + hr) * 64 + w_) * 256 + cc * 128 + c8);
                *reinterpret_cast<u16x8*>(&S3[(rr * 66 + w_ + 1) * 136 + c8]) = d;
            }
            __syncthreads();
            if (wv < 4) {
#pragma unroll
                for (int tp = 0; tp < 9; ++tp) {
                    int dh = tp / 3, dw = tp % 3;
                    const unsigned short* wb = wofT + (tp * 32 + lm) * 256 + cc * 128;
#pragma unroll
                    for (int kc = 0; kc < 4; ++kc) {
                        s16x8 a = *reinterpret_cast<const s16x8*>(
                            &S3[(dh * 66 + p0w + lm + dw) * 136 + kc * 32 + q * 8]);
                        s16x8 b0 = *reinterpret_cast<const s16x8*>(wb + kc * 32 + q * 8);
                        s16x8 b1 = *reinterpret_cast<const s16x8*>(wb + 16 * 256 + kc * 32 + q * 8);
                        oacc0 = __builtin_amdgcn_mfma_f32_16x16x32_bf16(a, b0, oacc0, 0, 0, 0);
                        oacc1 = __builtin_amdgcn_mfma_f32_16x16x32_bf16(a, b1, oacc1, 0, 0, 0);
                    }
                }
            }
        }
        if (wv < 4) {
#pragma unroll
            for (int n = 0; n < 2; ++n) {
                int j = n * 16 + lm;
                float bj = (j < 27) ? boffg[j] : 0.f;
                f32x4 a = n ? oacc1 : oacc0;
#pragma unroll
                for (int i = 0; i < 4; ++i)
                    OMS[(p0w + q * 4 + i) * 33 + j] = a[i] + bj;
            }
        }
        __syncthreads();   // OMS ready; S3 reads done before S writes
    }

    // ================= Phase B2: main GEMM (producer/consumer) ==============
    unsigned short* S = (unsigned short*)smem;               // [2][64*264]
    float* OMS = (float*)(smem + 67584);
    f32x4 acc[4][4];
#pragma unroll
    for (int m = 0; m < 4; ++m)
#pragma unroll
        for (int n = 0; n < 4; ++n) acc[m][n] = FZ;

    if (wv >= 4) {
        // ------------------------- producer -------------------------
        int pw = wv - 4;
        int s  = lane & 7;                 // 16B sub-chunk within 128B window
        int pA = pw * 16 + (lane >> 3);    // group A pixel (8 lanes each)
        int pB = pA + 8;                   // group B pixel
        int rb = b * 4096;

        float wgA[4], wgB[4];
        int   adA[4], adB[4];

        auto setup = [&](int tp, int p, float* wgt, int* ad) {
            float oh = OMS[p * 33 + 2 * tp];
            float ow = OMS[p * 33 + 2 * tp + 1];
            float mv = OMS[p * 33 + 18 + tp];
            float mk = 1.f / (1.f + __expf(-mv));
            float ph = (float)(h + tp / 3 - 1) + oh;
            float pw_ = (float)(p + tp % 3 - 1) + ow;
            float fh0 = floorf(ph), fw0 = floorf(pw_);
            int ih0 = (int)fh0, iw0 = (int)fw0;
            float lh = ph - fh0, lw = pw_ - fw0;
            float hh = 1.f - lh, hw_ = 1.f - lw;
            bool vh0 = (ih0 >= 0) & (ih0 < 64);
            bool vh1 = (ih0 + 1 >= 0) & (ih0 + 1 < 64);
            bool vw0 = (iw0 >= 0) & (iw0 < 64);
            bool vw1 = (iw0 + 1 >= 0) & (iw0 + 1 < 64);
            wgt[0] = hh * hw_ * mk * (float)(vh0 & vw0);
            wgt[1] = hh * lw  * mk * (float)(vh0 & vw1);
            wgt[2] = lh * hw_ * mk * (float)(vh1 & vw0);
            wgt[3] = lh * lw  * mk * (float)(vh1 & vw1);
            int ch0 = min(max(ih0, 0), 63), ch1 = min(max(ih0 + 1, 0), 63);
            int cw0 = min(max(iw0, 0), 63), cw1 = min(max(iw0 + 1, 0), 63);
            ad[0] = ((rb + ch0 * 64 + cw0) * 256);
            ad[1] = ((rb + ch0 * 64 + cw1) * 256);
            ad[2] = ((rb + ch1 * 64 + cw0) * 256);
            ad[3] = ((rb + ch1 * 64 + cw1) * 256);
        };

        u16x8 rP[4], rQ[4];
        auto issueSet = [&](const int* ad, int j, u16x8* r) {
            int off = j * 64 + s * 8;
#pragma unroll
            for (int c = 0; c < 4; ++c)
                r[c] = *reinterpret_cast<const u16x8*>(xT + ad[c] + off);
        };
        auto blendSet = [&](int buf, int p, const float* wgt, int j, u16x8* r) {
            u16x8 res;
#pragma unroll
            for (int k = 0; k < 8; ++k) {
                float v = wgt[0] * bf2f(r[0][k]);
                v = fmaf(wgt[1], bf2f(r[1][k]), v);
                v = fmaf(wgt[2], bf2f(r[2][k]), v);
                v = fmaf(wgt[3], bf2f(r[3][k]), v);
                res[k] = f2bf(v);
            }
            *reinterpret_cast<u16x8*>(&S[buf * 16896 + p * 264 + j * 64 + s * 8]) = res;
        };
        auto fillTap = [&](int tp, int buf) {
            setup(tp, pA, wgA, adA);
            setup(tp, pB, wgB, adB);
            issueSet(adA, 0, rP);
            issueSet(adA, 1, rQ);
            blendSet(buf, pA, wgA, 0, rP);  issueSet(adA, 2, rP);
            blendSet(buf, pA, wgA, 1, rQ);  issueSet(adA, 3, rQ);
            blendSet(buf, pA, wgA, 2, rP);  issueSet(adB, 0, rP);
            blendSet(buf, pA, wgA, 3, rQ);  issueSet(adB, 1, rQ);
            blendSet(buf, pB, wgB, 0, rP);  issueSet(adB, 2, rP);
            blendSet(buf, pB, wgB, 1, rQ);  issueSet(adB, 3, rQ);
            blendSet(buf, pB, wgB, 2, rP);
            blendSet(buf, pB, wgB, 3, rQ);
        };

        fillTap(0, 0);
        __syncthreads();
        for (int tp = 0; tp < 9; ++tp) {
            if (tp < 8) fillTap(tp + 1, (tp + 1) & 1);
            __syncthreads();
        }
    } else {
        // ------------------------- consumer -------------------------
        __syncthreads();               // matches producer prologue barrier
        for (int tp = 0; tp < 9; ++tp) {
            const unsigned short* Sc = &S[(tp & 1) * 16896];
            const unsigned short* wtap = wTk + (size_t)tp * 65536
                                       + (size_t)(wv * 4) * 512 + lm * 32 + q * 8;
            s16x8 wbuf[2][4];
#pragma unroll
            for (int n = 0; n < 4; ++n)
                wbuf[0][n] = *reinterpret_cast<const s16x8*>(wtap + n * 512);
#pragma unroll
            for (int kc = 0; kc < 8; ++kc) {
                if (kc < 7) {
                    const unsigned short* wb = wtap + (kc + 1) * 8192;
#pragma unroll
                    for (int n = 0; n < 4; ++n)
                        wbuf[(kc + 1) & 1][n] = *reinterpret_cast<const s16x8*>(wb + n * 512);
                }
#pragma unroll
                for (int mt = 0; mt < 4; ++mt) {
                    s16x8 a = *reinterpret_cast<const s16x8*>(
                        &Sc[(mt * 16 + lm) * 264 + kc * 32 + q * 8]);
#pragma unroll
                    for (int n = 0; n < 4; ++n)
                        acc[mt][n] = __builtin_amdgcn_mfma_f32_16x16x32_bf16(
                            a, wbuf[kc & 1][n], acc[mt][n], 0, 0, 0);
                }
            }
            __syncthreads();
        }
    }

    // ====== epilogue: y16 (bf16, tile layout) + stats (consumers only) ======
    if (wv < 4) {
        u16x4* yv = reinterpret_cast<u16x4*>(y16);
#pragma unroll
        for (int nt = 0; nt < 4; ++nt) {
            int o = wv * 64 + nt * 16 + lm;
            float bo = bias[o];
            float sacc = 0.f, ssacc = 0.f;
#pragma unroll
            for (int mt = 0; mt < 4; ++mt) {
                u16x4 st;
#pragma unroll
                for (int i = 0; i < 4; ++i) {
                    float v = acc[mt][nt][i] + bo;
                    st[i] = f2bf(v);
                    sacc += v; ssacc += v * v;
                }
                int idx4 = ((pblk * 4 + wv) * 16 + nt * 4 + mt) * 64 + lane;
                yv[idx4] = st;
            }
            sacc  += __shfl_xor(sacc, 16);
            sacc  += __shfl_xor(sacc, 32);
            ssacc += __shfl_xor(ssacc, 16);
            ssacc += __shfl_xor(ssacc, 32);
            if (q == 0) {
                atomicAdd(&gsum[o], sacc);
                atomicAdd(&gssq[o], ssacc);
            }
        }
    }
}

// ---------------------------------------------------------------------------
// 3) BN + ReLU + untile + transpose; float4 stores (16B/lane)
__global__ void k_bnrelu(const unsigned short* __restrict__ y16,
                         const float* __restrict__ gsum, const float* __restrict__ gssq,
                         const float* __restrict__ gamma, const float* __restrict__ beta,
                         float* __restrict__ out) {
    int blk = blockIdx.x;
    int b = blk & 7, h = blk >> 3;
    int pblk = b * 64 + h;
    __shared__ unsigned short T[64 * 257];
    __shared__ float sc[256], sh[256];
    int t = threadIdx.x;
    {
        const float n = 32768.f;
        float mean = gsum[t] / n;
        float var = gssq[t] / n - mean * mean;
        float inv = rsqrtf(var + 1e-5f);
        float s = gamma[t] * inv;
        sc[t] = s;
        sh[t] = beta[t] - mean * s;
    }
    const u16x4* yv = reinterpret_cast<const u16x4*>(y16) + pblk * 4096;
#pragma unroll
    for (int r = 0; r < 16; ++r) {
        int v = t + r * 256;
        u16x4 d = yv[v];
        int lane = v & 63, mt = (v >> 6) & 3, nt = (v >> 8) & 3, wvv = (v >> 10) & 3;
        int p = mt * 16 + (lane >> 4) * 4;
        int o = wvv * 64 + nt * 16 + (lane & 15);
        T[(p + 0) * 257 + o] = d[0];
        T[(p + 1) * 257 + o] = d[1];
        T[(p + 2) * 257 + o] = d[2];
        T[(p + 3) * 257 + o] = d[3];
    }
    __syncthreads();
    int w4   = (t & 15) * 4;
    int orow = t >> 4;
    float* obase = out + (size_t)b * (256 * 4096) + h * 64;
#pragma unroll
    for (int it = 0; it < 16; ++it) {
        int o = orow + it * 16;
        float scl = sc[o], shf = sh[o];
        float4 vo;
        vo.x = fmaxf(bf2f(T[(w4 + 0) * 257 + o]) * scl + shf, 0.f);
        vo.y = fmaxf(bf2f(T[(w4 + 1) * 257 + o]) * scl + shf, 0.f);
        vo.z = fmaxf(bf2f(T[(w4 + 2) * 257 + o]) * scl + shf, 0.f);
        vo.w = fmaxf(bf2f(T[(w4 + 3) * 257 + o]) * scl + shf, 0.f);
        *reinterpret_cast<float4*>(obase + (size_t)o * 4096 + w4) = vo;
    }
}

// ---------------------------------------------------------------------------
extern "C" void kernel_launch(void* const* d_in, const int* in_sizes, int n_in,
                              void* d_out, int out_size, void* d_ws, size_t ws_size,
                              hipStream_t stream) {
    const float* x      = (const float*)d_in[0];
    const float* w_off  = (const float*)d_in[1];
    const float* b_off  = (const float*)d_in[2];
    const float* weight = (const float*)d_in[3];
    const float* bias   = (const float*)d_in[4];
    const float* gamma  = (const float*)d_in[5];
    const float* beta   = (const float*)d_in[6];

    char* ws = (char*)d_ws;
    const size_t OFF_XT    = 0;                       // 16,777,216  bf16 xT
    const size_t OFF_WT    = OFF_XT + 16777216;       //  1,179,648  bf16 wTk
    const size_t OFF_WOFT  = OFF_WT + 1179648;        //    147,456  bf16 wofT
    const size_t OFF_Y16   = OFF_WOFT + 147456;       // 16,777,216  bf16 y tile-layout
    const size_t OFF_SUM   = OFF_Y16 + 16777216;      //      1,024
    const size_t OFF_SUMSQ = OFF_SUM + 1024;          //      1,024

    unsigned short* xT   = (unsigned short*)(ws + OFF_XT);
    unsigned short* wTk  = (unsigned short*)(ws + OFF_WT);
    unsigned short* wofT = (unsigned short*)(ws + OFF_WOFT);
    unsigned short* y16  = (unsigned short*)(ws + OFF_Y16);
    float* gsum  = (float*)(ws + OFF_SUM);
    float* gssq  = (float*)(ws + OFF_SUMSQ);

    hipMemsetAsync(ws + OFF_SUM, 0, 2048, stream);

    k_pack  <<<4640, 256, 0, stream>>>(x, weight, w_off, xT, wTk, wofT);
    k_main  <<< 512, 512, 0, stream>>>(xT, wTk, wofT, b_off, bias, y16, gsum, gssq);
    k_bnrelu<<< 512, 256, 0, stream>>>(y16, gsum, gssq, gamma, beta, (float*)d_out);
}